// Round 5
// baseline (661.672 us; speedup 1.0000x reference)
//
#include <hip/hip_runtime.h>
#include <cmath>

// ---------------- problem constants ----------------
constexpr int NUSER = 100000;
constexpr int NNEWS = 20000;
constexpr int CH    = 128;
constexpr int NE    = 250000;
constexpr int NTOT  = NNEWS + NUSER + NUSER;   // joint counter array (rel0|rel1|rel2)
constexpr int NSB   = (NTOT + 255) / 256;      // scan blocks = 860
constexpr int CLM   = 3 * NE - 1;              // clamp to LAST valid cl slot
// R4 BUG (absmax 0.16): CLM was 3*NE-2 and clamped the BASE index -> the dst owning the
// final CSR slot read cl[3*NE-2] instead of cl[3*NE-1] (one swapped K/V row). The base
// read is already guarded by na>0 (=> in-bounds); only the +1 read needs its own clamp.

typedef _Float16 f16x8 __attribute__((ext_vector_type(8)));
typedef _Float16 f16x4 __attribute__((ext_vector_type(4)));
typedef _Float16 f16x2 __attribute__((ext_vector_type(2)));
typedef float    f32x4 __attribute__((ext_vector_type(4)));

// ---------------- workspace layout (float units) ----------------
constexpr size_t OFF_QU  = 0;                                   // q_user fp16 [NUSER*128]
constexpr size_t OFF_QN  = OFF_QU  + (size_t)NUSER * 64;        // q_news fp16
constexpr size_t OFF_AGU = OFF_QN  + (size_t)NNEWS * 64;        // agg_user fp16 (gelu'd)
constexpr size_t OFF_AGN = OFF_AGU + (size_t)NUSER * 64;        // agg_news fp16 (gelu'd)
constexpr size_t OFF_KVB = OFF_AGN + (size_t)NNEWS * 64;        // kv_big fp16 [NUSER][256] (k|v interleaved)
constexpr size_t OFF_KVS = OFF_KVB + (size_t)NUSER * 128;       // kv_sm  fp16 [NNEWS][256]
constexpr size_t OFF_WF  = OFF_KVS + (size_t)NNEWS * 128;       // swizzled fp16 frags, BOTH layers (20 matrices)
constexpr size_t OFF_BE  = OFF_WF  + 20 * 8192;                 // bke[2][3][128] + bve[2][3][128] f32
constexpr size_t OFF_INT = OFF_BE  + 2 * 768;
// int offsets (relative, units: int)
constexpr size_t IO_CU   = 0;                    // joint counters [NTOT]
constexpr size_t IO_JRP  = IO_CU  + NTOT;        // joint row_ptr [NTOT+1]
constexpr size_t IO_BSUM = IO_JRP + NTOT + 1;    // scan partials [NSB]
constexpr size_t IO_BOFF = IO_BSUM + NSB;        // scan offsets  [NSB]
constexpr size_t IO_CL   = IO_BOFF + NSB;        // col (src per CSR slot) [3*NE]
constexpr size_t IO_RANK = IO_CL + 3 * NE;       // per-edge rank within dst [3*NE]
constexpr size_t IO_END  = IO_RANK + 3 * NE;
// fp16 activation side-channel (R2: GEMMs are bytes-bound; fp32 x was read 3-4x/layer)
constexpr size_t OFF_X16U = OFF_INT + IO_END;                   // x16 user fp16 [NUSER*128]
constexpr size_t OFF_X16N = OFF_X16U + (size_t)NUSER * 64;      // x16 news fp16

__device__ __forceinline__ float gelu_f(float x) {
    return 0.5f * x * (1.0f + erff(x * 0.70710678118654752440f));
}

// ---------------- swizzled-fragment dest index ----------------
// MFMA 16x16x32 fragment (lane,j): idx = lane&15, k = (lane>>4)*8 + j.
// Wf layout: [kt][ct][lane][j] contiguous -> coalesced b128 stage, conflict-free ds_read_b128.
__device__ __forceinline__ int frag_dest(int k, int col) {
    int kt = k >> 5, quad = (k >> 3) & 3, j = k & 7;
    int ct = col >> 4, m = col & 15;
    int lane = quad * 16 + m;
    return ((kt * 8 + ct) * 64 + lane) * 8 + j;
}

// ---------------- flat weight prep (both layers) + counter zeroing, one dispatch ----------------
constexpr int NEFF = 2 * 2 * 3 * 16384;   // 196608
constexpr int NCVT = 2 * 4 * 16384;       // 131072
constexpr int NBIA = 2 * 2 * 3 * 128;     // 1536
constexpr int NPREP = NEFF + NCVT + NBIA;

__global__ __launch_bounds__(256) void prep_weights_kernel(
    const float* __restrict__ Wk, const float* __restrict__ bk,
    const float* __restrict__ Wv, const float* __restrict__ bv,
    const float* __restrict__ Wq, const float* __restrict__ Wa,
    const float* __restrict__ a_rel, const float* __restrict__ m_rel,
    const float* __restrict__ p_rel,
    _Float16* __restrict__ wkf, float* __restrict__ bke,
    _Float16* __restrict__ wvf, float* __restrict__ bve,
    _Float16* __restrict__ wqf, _Float16* __restrict__ waf,
    int* __restrict__ cu)
{
    const float kscale = 0.17677669529663688f * 1.44269504088896340f;  // 1/sqrt(32)*log2(e)
    int idx = blockIdx.x * 256 + threadIdx.x;
    if (idx < NEFF) {
        int o = idx & 16383;
        int g = idx >> 14;          // (l*2+kind)*3 + r
        int r = g % 3, lk = g / 3, kind = lk & 1, l = lk >> 1;
        int st = (r == 1) ? 1 : 0;
        const float* W   = (kind ? Wv : Wk) + ((size_t)(l * 2 + st)) * 16384;
        const float* rel = (kind ? m_rel : a_rel) + ((size_t)(l * 3 + r)) * 4096;
        _Float16* Wf = (kind ? wvf : wkf) + ((size_t)(l * 3 + r)) * 16384;
        int k = o >> 7, col = o & 127, h = col >> 5, e = col & 31;
        const float* wrow = W + (size_t)k * 128 + h * 32;
        const float* rcol = rel + h * 1024 + e;
        float s = 0.f;
        #pragma unroll
        for (int d = 0; d < 32; ++d) s += wrow[d] * rcol[d * 32];
        if (kind == 0) s *= p_rel[(l * 3 + r) * 4 + h] * kscale;
        Wf[frag_dest(k, col)] = (_Float16)s;
    } else if (idx < NEFF + NCVT) {
        int t = idx - NEFF;
        int o = t & 16383;
        int b = t >> 14;            // l*4 + sub  (sub 0,1: Wq types; 2,3: Wa types)
        int l = b >> 2, sub = b & 3;
        const float* W;
        _Float16* Wf;
        if (sub < 2) { W = Wq + ((size_t)(l * 2 + sub)) * 16384;     Wf = wqf + ((size_t)(l * 2 + sub)) * 16384; }
        else         { W = Wa + ((size_t)(l * 2 + sub - 2)) * 16384; Wf = waf + ((size_t)(l * 2 + sub - 2)) * 16384; }
        int k = o >> 7, col = o & 127;
        Wf[frag_dest(k, col)] = (_Float16)W[o];
    } else if (idx < NPREP) {
        int t = idx - NEFF - NCVT;
        int col = t & 127;
        int g = t >> 7;
        int r = g % 3, lk = g / 3, kind = lk & 1, l = lk >> 1;
        int st = (r == 1) ? 1 : 0;
        const float* bi  = (kind ? bv : bk) + ((size_t)(l * 2 + st)) * 128;
        const float* rel = (kind ? m_rel : a_rel) + ((size_t)(l * 3 + r)) * 4096;
        float* be = (kind ? bve : bke) + (size_t)l * 384 + r * 128;
        int h = col >> 5, e = col & 31;
        float s = 0.f;
        #pragma unroll
        for (int d = 0; d < 32; ++d) s += bi[h * 32 + d] * rel[h * 1024 + d * 32 + e];
        if (kind == 0) s *= p_rel[(l * 3 + r) * 4 + h] * kscale;
        be[col] = s;
    } else if (idx < NPREP + NTOT) {
        cu[idx - NPREP] = 0;       // zero the CSR counters (fused: saves a dispatch)
    }
}

// ---------------- CSR build: hist + per-edge rank (atomics), scan, atomic-free fill ----------------
__global__ void histrank_kernel(const int* __restrict__ e0, const int* __restrict__ e1,
                                const int* __restrict__ e2, int* __restrict__ cu,
                                int* __restrict__ rank) {
    int idx = blockIdx.x * 256 + threadIdx.x;
    if (idx >= 3 * NE) return;
    int r = idx / NE, e = idx - r * NE;
    const int* ei = (r == 0) ? e0 : (r == 1) ? e1 : e2;
    int base = (r == 0) ? 0 : (r == 1) ? NNEWS : (NNEWS + NUSER);
    rank[idx] = atomicAdd(&cu[base + ei[NE + e]], 1);
}

__global__ __launch_bounds__(256) void scan_part_kernel(const int* __restrict__ cu,
                                                        int* __restrict__ bsum) {
    int i = blockIdx.x * 256 + threadIdx.x;
    int v = (i < NTOT) ? cu[i] : 0;
    #pragma unroll
    for (int o = 1; o < 64; o <<= 1) v += __shfl_xor(v, o);
    __shared__ int ws_[4];
    if ((threadIdx.x & 63) == 0) ws_[threadIdx.x >> 6] = v;
    __syncthreads();
    if (threadIdx.x == 0) bsum[blockIdx.x] = ws_[0] + ws_[1] + ws_[2] + ws_[3];
}

__global__ __launch_bounds__(1024) void scan_top_kernel(const int* __restrict__ bsum,
                                                        int* __restrict__ boff,
                                                        int* __restrict__ jrp) {
    __shared__ int wsum[16];
    int tid = threadIdx.x, lane = tid & 63, w = tid >> 6;
    int v = (tid < NSB) ? bsum[tid] : 0;
    int x = v;
    #pragma unroll
    for (int o = 1; o < 64; o <<= 1) { int y = __shfl_up(x, o); if (lane >= o) x += y; }
    if (lane == 63) wsum[w] = x;
    __syncthreads();
    if (tid < 16) {
        int t = wsum[tid];
        #pragma unroll
        for (int o = 1; o < 16; o <<= 1) { int y = __shfl_up(t, o); if (tid >= o) t += y; }
        wsum[tid] = t;
    }
    __syncthreads();
    int woff = w ? wsum[w - 1] : 0;
    if (tid < NSB) boff[tid] = woff + x - v;
    if (tid == 0) jrp[NTOT] = 3 * NE;
}

__global__ __launch_bounds__(256) void scan_fin_kernel(const int* __restrict__ cu,
                                                       const int* __restrict__ boff,
                                                       int* __restrict__ jrp) {
    __shared__ int wsum[4];
    int tid = threadIdx.x, lane = tid & 63, w = tid >> 6;
    int i = blockIdx.x * 256 + tid;
    int v = (i < NTOT) ? cu[i] : 0;
    int x = v;
    #pragma unroll
    for (int o = 1; o < 64; o <<= 1) { int y = __shfl_up(x, o); if (lane >= o) x += y; }
    if (lane == 63) wsum[w] = x;
    __syncthreads();
    int woff = 0;
    #pragma unroll
    for (int k = 0; k < 4; ++k) if (k < w) woff += wsum[k];
    int excl = boff[blockIdx.x] + woff + x - v;
    if (i < NTOT) jrp[i] = excl;
}

__global__ void fill_kernel(const int* __restrict__ e0, const int* __restrict__ e1,
                            const int* __restrict__ e2, const int* __restrict__ jrp,
                            const int* __restrict__ rank, int* __restrict__ cl) {
    int idx = blockIdx.x * 256 + threadIdx.x;
    if (idx >= 3 * NE) return;
    int r = idx / NE, e = idx - r * NE;
    const int* ei = (r == 0) ? e0 : (r == 1) ? e1 : e2;
    int base = (r == 0) ? 0 : (r == 1) ? NNEWS : (NNEWS + NUSER);
    int dst = ei[NE + e], src = ei[e];
    cl[jrp[base + dst] + rank[idx]] = src;   // no atomics (R8: fill3 = 46 us of atomic latency)
}

// ---------------- MFMA GEMM v7: LDS weights, grid-stride balanced tiles ----------------
// R3: 391-block (NOUT=2) / 782-block (NOUT=1) grids at 2/5-blocks-per-CU residency leave
// a 1.33-2x CU imbalance (eff ~76%). v7 launches a residency-shaped grid (512 / 1024)
// and grid-strides over tiles -> every CU gets ~equal tiles. Register double-buffer kept.
template<int NOUT, bool IN_HALF, bool GELU_IN, bool SKIP_OUT, bool OUT_HALF,
         bool XOLD_HALF, bool WRITE_X16>
__global__ __launch_bounds__(256) void gemm_v7(
    const void* __restrict__ Ain,
    const _Float16* __restrict__ Wf0, const _Float16* __restrict__ Wf1,
    const float* __restrict__ b0, const float* __restrict__ b1,
    void* out0, void* out1, int ostride,
    int N, const float* __restrict__ skipv, const void* Xold,
    _Float16* x16out)
{
    __shared__ _Float16 sW[NOUT * 16384];   // 32 KB per weight matrix
    const int tid = threadIdx.x;
    const int lane = tid & 63;
    const int m = lane & 15, quad = lane >> 4, wave = tid >> 6;
    const int tstride = gridDim.x;

    // named double buffers (never runtime-indexed -> stay in VGPRs)
    f32x4 xc32_0, xc32_1, xc32_2, xc32_3, xc32_4, xc32_5, xc32_6, xc32_7;
    f32x4 xn32_0, xn32_1, xn32_2, xn32_3, xn32_4, xn32_5, xn32_6, xn32_7;
    f16x8 xc16_0, xc16_1, xc16_2, xc16_3;
    f16x8 xn16_0, xn16_1, xn16_2, xn16_3;

#define LOADX_NEXT(tt)                                                              \
    do {                                                                            \
        int node_ = (tt) * 64 + wave * 16 + m;                                      \
        if (node_ > N - 1) node_ = N - 1;                                           \
        if constexpr (IN_HALF) {                                                    \
            const _Float16* A_ = (const _Float16*)Ain + (size_t)node_ * 128 + quad * 8; \
            xn16_0 = *(const f16x8*)(A_);                                           \
            xn16_1 = *(const f16x8*)(A_ + 32);                                      \
            xn16_2 = *(const f16x8*)(A_ + 64);                                      \
            xn16_3 = *(const f16x8*)(A_ + 96);                                      \
        } else {                                                                    \
            const float* A_ = (const float*)Ain + (size_t)node_ * 128 + quad * 8;   \
            xn32_0 = *(const f32x4*)(A_);        xn32_1 = *(const f32x4*)(A_ + 4);  \
            xn32_2 = *(const f32x4*)(A_ + 32);   xn32_3 = *(const f32x4*)(A_ + 36); \
            xn32_4 = *(const f32x4*)(A_ + 64);   xn32_5 = *(const f32x4*)(A_ + 68); \
            xn32_6 = *(const f32x4*)(A_ + 96);   xn32_7 = *(const f32x4*)(A_ + 100);\
        }                                                                           \
    } while (0)

#define ROTATE_X()                                                                  \
    do {                                                                            \
        if constexpr (IN_HALF) {                                                    \
            xc16_0 = xn16_0; xc16_1 = xn16_1; xc16_2 = xn16_2; xc16_3 = xn16_3;     \
        } else {                                                                    \
            xc32_0 = xn32_0; xc32_1 = xn32_1; xc32_2 = xn32_2; xc32_3 = xn32_3;     \
            xc32_4 = xn32_4; xc32_5 = xn32_5; xc32_6 = xn32_6; xc32_7 = xn32_7;     \
        }                                                                           \
    } while (0)

    // tile-0 x prefetch, issued before LDS staging so HBM latency hides under it
    LOADX_NEXT(blockIdx.x);
    ROTATE_X();

    for (int i = tid; i < NOUT * 2048; i += 256) {
        const _Float16* src = (NOUT == 1 || i < 2048) ? (Wf0 + (size_t)i * 8)
                                                      : (Wf1 + (size_t)(i - 2048) * 8);
        *(f16x8*)(sW + (size_t)i * 8) = *(const f16x8*)src;
    }
    __syncthreads();

    float aS = 0.f, bSk = 0.f;
    if constexpr (SKIP_OUT) {
        float sv = skipv[0];
        aS = 1.0f / (1.0f + expf(-sv));
        bSk = 1.0f - aS;
    }

    for (int tile = blockIdx.x; tile * 64 < N; tile += tstride) {
        const int node  = tile * 64 + wave * 16 + m;
        const int nodec = (node < N) ? node : (N - 1);

        // issue NEXT tile's x loads before this tile's compute (clamped; loop cond guards use)
        LOADX_NEXT(tile + tstride);

        // skip-path residual, loaded early so it completes under the MFMAs
        f32x4 xo0, xo1, xo2, xo3, xo4, xo5, xo6, xo7;
        f16x4 xh0, xh1, xh2, xh3, xh4, xh5, xh6, xh7;
        if constexpr (SKIP_OUT) {
            if constexpr (XOLD_HALF) {
                const _Float16* Xo = (const _Float16*)Xold + (size_t)nodec * 128 + quad * 4;
                xh0 = *(const f16x4*)(Xo);        xh1 = *(const f16x4*)(Xo + 16);
                xh2 = *(const f16x4*)(Xo + 32);   xh3 = *(const f16x4*)(Xo + 48);
                xh4 = *(const f16x4*)(Xo + 64);   xh5 = *(const f16x4*)(Xo + 80);
                xh6 = *(const f16x4*)(Xo + 96);   xh7 = *(const f16x4*)(Xo + 112);
            } else {
                const float* Xo = (const float*)Xold + (size_t)nodec * 128 + quad * 4;
                xo0 = *(const f32x4*)(Xo);       xo1 = *(const f32x4*)(Xo + 16);
                xo2 = *(const f32x4*)(Xo + 32);  xo3 = *(const f32x4*)(Xo + 48);
                xo4 = *(const f32x4*)(Xo + 64);  xo5 = *(const f32x4*)(Xo + 80);
                xo6 = *(const f32x4*)(Xo + 96);  xo7 = *(const f32x4*)(Xo + 112);
            }
        }

        // convert current x to MFMA B-frags
        f16x8 xf[4];
        if constexpr (IN_HALF) {
            xf[0] = xc16_0; xf[1] = xc16_1; xf[2] = xc16_2; xf[3] = xc16_3;
            if constexpr (GELU_IN) {
                #pragma unroll
                for (int kt = 0; kt < 4; ++kt)
                    #pragma unroll
                    for (int j = 0; j < 8; ++j) xf[kt][j] = (_Float16)gelu_f((float)xf[kt][j]);
            }
        } else {
            f32x4 a0[4] = {xc32_0, xc32_2, xc32_4, xc32_6};
            f32x4 a1[4] = {xc32_1, xc32_3, xc32_5, xc32_7};
            #pragma unroll
            for (int kt = 0; kt < 4; ++kt) {
                f32x4 u = a0[kt], v = a1[kt];
                if constexpr (GELU_IN) {
                    #pragma unroll
                    for (int j = 0; j < 4; ++j) { u[j] = gelu_f(u[j]); v[j] = gelu_f(v[j]); }
                }
                xf[kt] = (f16x8){(_Float16)u[0], (_Float16)u[1], (_Float16)u[2], (_Float16)u[3],
                                 (_Float16)v[0], (_Float16)v[1], (_Float16)v[2], (_Float16)v[3]};
            }
        }

        // fp16 activation side-channel: persist the converted x (layer-0 q GEMMs)
        if constexpr (WRITE_X16) {
            if (node < N) {
                _Float16* xd = x16out + (size_t)node * 128 + quad * 8;
                *(f16x8*)(xd)      = xf[0];
                *(f16x8*)(xd + 32) = xf[1];
                *(f16x8*)(xd + 64) = xf[2];
                *(f16x8*)(xd + 96) = xf[3];
            }
        }

        f32x4 acc0[8], acc1[8];
        #pragma unroll
        for (int u = 0; u < 8; ++u) {
            acc0[u] = (f32x4){0.f, 0.f, 0.f, 0.f};
            if constexpr (NOUT > 1) acc1[u] = (f32x4){0.f, 0.f, 0.f, 0.f};
        }

        #pragma unroll
        for (int kt = 0; kt < 4; ++kt) {
            #pragma unroll
            for (int ct = 0; ct < 8; ++ct) {
                f16x8 wf0 = *(const f16x8*)(sW + ((kt * 8 + ct) * 64 + lane) * 8);
                acc0[ct] = __builtin_amdgcn_mfma_f32_16x16x32_f16(wf0, xf[kt], acc0[ct], 0, 0, 0);
                if constexpr (NOUT > 1) {
                    f16x8 wf1 = *(const f16x8*)(sW + 16384 + ((kt * 8 + ct) * 64 + lane) * 8);
                    acc1[ct] = __builtin_amdgcn_mfma_f32_16x16x32_f16(wf1, xf[kt], acc1[ct], 0, 0, 0);
                }
            }
        }

        if (node < N) {
            f32x4 xoa[8];
            if constexpr (SKIP_OUT) {
                if constexpr (XOLD_HALF) {
                    f16x4 xhh[8] = {xh0, xh1, xh2, xh3, xh4, xh5, xh6, xh7};
                    #pragma unroll
                    for (int ct = 0; ct < 8; ++ct)
                        xoa[ct] = (f32x4){(float)xhh[ct][0], (float)xhh[ct][1],
                                          (float)xhh[ct][2], (float)xhh[ct][3]};
                } else {
                    xoa[0] = xo0; xoa[1] = xo1; xoa[2] = xo2; xoa[3] = xo3;
                    xoa[4] = xo4; xoa[5] = xo5; xoa[6] = xo6; xoa[7] = xo7;
                }
            }
            #pragma unroll
            for (int ct = 0; ct < 8; ++ct) {
                int c = ct * 16 + quad * 4;      // out-channel base for this lane's 4 regs
                {
                    f32x4 r = acc0[ct] + *(const f32x4*)(b0 + c);
                    if constexpr (SKIP_OUT) {
                        #pragma unroll
                        for (int j = 0; j < 4; ++j) r[j] = fmaxf(aS * r[j] + bSk * xoa[ct][j], 0.f);
                    }
                    if constexpr (OUT_HALF) {
                        f16x4 h = {(_Float16)r[0], (_Float16)r[1], (_Float16)r[2], (_Float16)r[3]};
                        *(f16x4*)((_Float16*)out0 + (size_t)node * ostride + c) = h;
                    } else {
                        *(f32x4*)((float*)out0 + (size_t)node * ostride + c) = r;
                    }
                }
                if constexpr (NOUT > 1) {
                    f32x4 r = acc1[ct] + *(const f32x4*)(b1 + c);
                    f16x4 h = {(_Float16)r[0], (_Float16)r[1], (_Float16)r[2], (_Float16)r[3]};
                    *(f16x4*)((_Float16*)out1 + (size_t)node * ostride + c) = h;
                }
            }
        }

        ROTATE_X();
    }
#undef LOADX_NEXT
#undef ROTATE_X
}

// ---------------- attention v7 (R4 design + CLM fix) ----------------
//  - MODE 1 (user): the TWO relations are independent -> merge their edge loops. 4 useful
//    gather chains in flight, dependent rounds E[max(pA,pB)] ~= 2.6 vs 4.7 sequential.
//  - MODE 0 (news, deg 12.5): 1-iteration-ahead ping-pong kv prefetch (long loops).
//  - persistent grid-stride dst loop (user grid 2048) to kill block churn (occupancy 54%).
template<int MODE>
__global__ __launch_bounds__(256) void attn_v7(
    const _Float16* __restrict__ q,
    const _Float16* __restrict__ kv1, const int* __restrict__ rp1,
    const _Float16* __restrict__ kv2, const int* __restrict__ rp2,
    const int* __restrict__ cl,
    _Float16* __restrict__ agg, int Ndst)
{
    const int sub = threadIdx.x & 15;
    const int grp = threadIdx.x >> 4;
    const int dstride = gridDim.x * 16;

    for (int d = blockIdx.x * 16 + grp; d < Ndst; d += dstride) {
        f16x8 qh = *(const f16x8*)(q + (size_t)d * 128 + sub * 8);
        const f16x2* qp = (const f16x2*)&qh;
        float acc[8] = {0.f, 0.f, 0.f, 0.f, 0.f, 0.f, 0.f, 0.f};

        if constexpr (MODE == 1) {
            int ea = rp1[d], e1a = rp1[d + 1];
            int eb = rp2[d], e1b = rp2[d + 1];
            float dena = 0.f, denb = 0.f;
            float sa[8] = {0.f, 0.f, 0.f, 0.f, 0.f, 0.f, 0.f, 0.f};
            float sb[8] = {0.f, 0.f, 0.f, 0.f, 0.f, 0.f, 0.f, 0.f};
            while (ea < e1a || eb < e1b) {
                int na = e1a - ea, nb = e1b - eb;
                // clamps keep the UNCONDITIONAL loads in-bounds; guards (na/nb) make the
                // values matter only when the unclamped index was valid (R4 fix).
                int eac  = (ea < CLM) ? ea : CLM;
                int eac1 = (ea + 1 < CLM) ? ea + 1 : CLM;
                int ebc  = (eb < CLM) ? eb : CLM;
                int ebc1 = (eb + 1 < CLM) ? eb + 1 : CLM;
                int ia0 = (na > 0) ? cl[eac] : 0;
                int ia1 = (na > 1) ? cl[eac1] : ia0;
                int ib0 = (nb > 0) ? cl[ebc] : 0;
                int ib1 = (nb > 1) ? cl[ebc1] : ib0;
                const _Float16* ra0 = kv1 + (size_t)ia0 * 256 + sub * 8;
                const _Float16* ra1 = kv1 + (size_t)ia1 * 256 + sub * 8;
                const _Float16* rb0 = kv2 + (size_t)ib0 * 256 + sub * 8;
                const _Float16* rb1 = kv2 + (size_t)ib1 * 256 + sub * 8;
                f16x8 ka0 = *(const f16x8*)(ra0), va0 = *(const f16x8*)(ra0 + 128);
                f16x8 ka1 = *(const f16x8*)(ra1), va1 = *(const f16x8*)(ra1 + 128);
                f16x8 kb0 = *(const f16x8*)(rb0), vb0 = *(const f16x8*)(rb0 + 128);
                f16x8 kb1 = *(const f16x8*)(rb1), vb1 = *(const f16x8*)(rb1 + 128);
                float pa0 = 0.f, pa1 = 0.f, pb0 = 0.f, pb1 = 0.f;
#if __has_builtin(__builtin_amdgcn_fdot2)
                const f16x2* xa0 = (const f16x2*)&ka0;
                const f16x2* xa1 = (const f16x2*)&ka1;
                const f16x2* xb0 = (const f16x2*)&kb0;
                const f16x2* xb1 = (const f16x2*)&kb1;
                #pragma unroll
                for (int j = 0; j < 4; ++j) {
                    pa0 = __builtin_amdgcn_fdot2(xa0[j], qp[j], pa0, false);
                    pa1 = __builtin_amdgcn_fdot2(xa1[j], qp[j], pa1, false);
                    pb0 = __builtin_amdgcn_fdot2(xb0[j], qp[j], pb0, false);
                    pb1 = __builtin_amdgcn_fdot2(xb1[j], qp[j], pb1, false);
                }
#else
                #pragma unroll
                for (int j = 0; j < 8; ++j) {
                    pa0 += (float)ka0[j] * (float)qh[j];
                    pa1 += (float)ka1[j] * (float)qh[j];
                    pb0 += (float)kb0[j] * (float)qh[j];
                    pb1 += (float)kb1[j] * (float)qh[j];
                }
#endif
                pa0 += __shfl_xor(pa0, 1); pa1 += __shfl_xor(pa1, 1);
                pb0 += __shfl_xor(pb0, 1); pb1 += __shfl_xor(pb1, 1);
                pa0 += __shfl_xor(pa0, 2); pa1 += __shfl_xor(pa1, 2);
                pb0 += __shfl_xor(pb0, 2); pb1 += __shfl_xor(pb1, 2);
                float wa0 = (na > 0) ? exp2f(pa0) : 0.f;
                float wa1 = (na > 1) ? exp2f(pa1) : 0.f;
                float wb0 = (nb > 0) ? exp2f(pb0) : 0.f;
                float wb1 = (nb > 1) ? exp2f(pb1) : 0.f;
                dena += wa0 + wa1;
                denb += wb0 + wb1;
                #pragma unroll
                for (int j = 0; j < 8; ++j) {
                    sa[j] += wa0 * (float)va0[j] + wa1 * (float)va1[j];
                    sb[j] += wb0 * (float)vb0[j] + wb1 * (float)vb1[j];
                }
                ea += 2; eb += 2;
            }
            if (dena > 0.f) {
                float inv = 1.f / dena;
                #pragma unroll
                for (int j = 0; j < 8; ++j) acc[j] += sa[j] * inv;
            }
            if (denb > 0.f) {
                float inv = 1.f / denb;
                #pragma unroll
                for (int j = 0; j < 8; ++j) acc[j] += sb[j] * inv;
            }
        } else {
            // single relation, 1-iteration-ahead pipelined pair prefetch
            int e = rp1[d], e1 = rp1[d + 1];
            float den = 0.f;
            float s[8] = {0.f, 0.f, 0.f, 0.f, 0.f, 0.f, 0.f, 0.f};
            if (e < e1) {
                int i0 = cl[e];
                int i1 = (e + 1 < e1) ? cl[e + 1] : i0;
                const _Float16* r0 = kv1 + (size_t)i0 * 256 + sub * 8;
                const _Float16* r1 = kv1 + (size_t)i1 * 256 + sub * 8;
                f16x8 k0 = *(const f16x8*)(r0), v0 = *(const f16x8*)(r0 + 128);
                f16x8 k1 = *(const f16x8*)(r1), v1 = *(const f16x8*)(r1 + 128);
                while (e < e1) {
                    int en = e + 2;
                    int enc  = (en < CLM) ? en : CLM;
                    int enc1 = (en + 1 < CLM) ? en + 1 : CLM;
                    int j0 = (en < e1) ? cl[enc] : 0;
                    int j1 = (en + 1 < e1) ? cl[enc1] : j0;
                    const _Float16* rn0 = kv1 + (size_t)j0 * 256 + sub * 8;
                    const _Float16* rn1 = kv1 + (size_t)j1 * 256 + sub * 8;
                    f16x8 kn0 = *(const f16x8*)(rn0), vn0 = *(const f16x8*)(rn0 + 128);
                    f16x8 kn1 = *(const f16x8*)(rn1), vn1 = *(const f16x8*)(rn1 + 128);
                    float p0 = 0.f, p1 = 0.f;
#if __has_builtin(__builtin_amdgcn_fdot2)
                    const f16x2* a0 = (const f16x2*)&k0;
                    const f16x2* a1 = (const f16x2*)&k1;
                    #pragma unroll
                    for (int j = 0; j < 4; ++j) {
                        p0 = __builtin_amdgcn_fdot2(a0[j], qp[j], p0, false);
                        p1 = __builtin_amdgcn_fdot2(a1[j], qp[j], p1, false);
                    }
#else
                    #pragma unroll
                    for (int j = 0; j < 8; ++j) {
                        p0 += (float)k0[j] * (float)qh[j];
                        p1 += (float)k1[j] * (float)qh[j];
                    }
#endif
                    p0 += __shfl_xor(p0, 1); p1 += __shfl_xor(p1, 1);
                    p0 += __shfl_xor(p0, 2); p1 += __shfl_xor(p1, 2);
                    float w0 = exp2f(p0);
                    float w1 = (e + 1 < e1) ? exp2f(p1) : 0.f;
                    den += w0 + w1;
                    #pragma unroll
                    for (int j = 0; j < 8; ++j) s[j] += w0 * (float)v0[j] + w1 * (float)v1[j];
                    k0 = kn0; v0 = vn0; k1 = kn1; v1 = vn1;
                    e = en;
                }
            }
            if (den > 0.f) {
                float inv = 1.f / den;
                #pragma unroll
                for (int j = 0; j < 8; ++j) acc[j] += s[j] * inv;
            }
        }

        f16x8 o;
        #pragma unroll
        for (int j = 0; j < 8; ++j) o[j] = (_Float16)gelu_f(acc[j]);   // gelu fused
        *(f16x8*)(agg + (size_t)d * 128 + sub * 8) = o;
    }
}

// ---------------- orchestration ----------------
extern "C" void kernel_launch(void* const* d_in, const int* in_sizes, int n_in,
                              void* d_out, int out_size, void* d_ws, size_t ws_size,
                              hipStream_t stream)
{
    const float* x_user = (const float*)d_in[0];
    const float* x_news = (const float*)d_in[1];
    const int* ei0 = (const int*)d_in[2];
    const int* ei1 = (const int*)d_in[3];
    const int* ei2 = (const int*)d_in[4];
    const float* Wk = (const float*)d_in[5];
    const float* bk = (const float*)d_in[6];
    const float* Wq = (const float*)d_in[7];
    const float* bq = (const float*)d_in[8];
    const float* Wv = (const float*)d_in[9];
    const float* bv = (const float*)d_in[10];
    const float* Wa = (const float*)d_in[11];
    const float* ba = (const float*)d_in[12];
    const float* skip = (const float*)d_in[13];
    const float* a_rel = (const float*)d_in[14];
    const float* m_rel = (const float*)d_in[15];
    const float* p_rel = (const float*)d_in[16];

    float* ws = (float*)d_ws;
    _Float16* q_user  = (_Float16*)(ws + OFF_QU);
    _Float16* q_news  = (_Float16*)(ws + OFF_QN);
    _Float16* agg_u   = (_Float16*)(ws + OFF_AGU);
    _Float16* agg_n   = (_Float16*)(ws + OFF_AGN);
    _Float16* kv_big  = (_Float16*)(ws + OFF_KVB);
    _Float16* kv_sm   = (_Float16*)(ws + OFF_KVS);
    _Float16* wkf = (_Float16*)(ws + OFF_WF);       // [2][3] matrices
    _Float16* wvf = wkf + 6 * 16384;                // [2][3]
    _Float16* wqf = wvf + 6 * 16384;                // [2][2]
    _Float16* waf = wqf + 4 * 16384;                // [2][2]
    float* bke = ws + OFF_BE;                       // [2][3][128]
    float* bve = bke + 768;
    int* ib   = (int*)(ws + OFF_INT);
    int* cu   = ib + IO_CU;
    int* jrp  = ib + IO_JRP;
    int* bsum = ib + IO_BSUM;
    int* boff = ib + IO_BOFF;
    int* cl   = ib + IO_CL;
    int* rank = ib + IO_RANK;
    _Float16* x16u = (_Float16*)(ws + OFF_X16U);    // fp16 activation side-channel
    _Float16* x16n = (_Float16*)(ws + OFF_X16N);
    const int* rp0 = jrp;
    const int* rp1 = jrp + NNEWS;
    const int* rp2 = jrp + NNEWS + NUSER;

    // ---- weight prep (both layers) + counter zero, one flat dispatch ----
    prep_weights_kernel<<<(NPREP + NTOT + 255) / 256, 256, 0, stream>>>(
        Wk, bk, Wv, bv, Wq, Wa, a_rel, m_rel, p_rel,
        wkf, bke, wvf, bve, wqf, waf, cu);

    // ---- CSR build: hist+rank (atomics) -> scan -> atomic-free fill ----
    int g3e = (3 * NE + 255) / 256;
    histrank_kernel<<<g3e, 256, 0, stream>>>(ei0, ei1, ei2, cu, rank);
    scan_part_kernel<<<NSB, 256, 0, stream>>>(cu, bsum);
    scan_top_kernel<<<1, 1024, 0, stream>>>(bsum, boff, jrp);
    scan_fin_kernel<<<NSB, 256, 0, stream>>>(cu, boff, jrp);
    fill_kernel<<<g3e, 256, 0, stream>>>(ei0, ei1, ei2, jrp, rank, cl);

    float* out_user = (float*)d_out;
    float* out_news = (float*)d_out + (size_t)NUSER * CH;

    // residency-shaped grids (grid-stride tile loops inside)
    constexpr int GU1 = 1024;   // NOUT=1 user: 4 blocks/CU (32KB LDS), 1563 tiles -> 1-2 each
    constexpr int GU2 = 512;    // NOUT=2 user: 2 blocks/CU (64KB LDS cap), ~3 tiles each
    int gbN  = (NNEWS + 63) / 64;   // news: 313 tiny blocks, single round

    for (int l = 0; l < 2; ++l) {
        _Float16* wkf_l = wkf + (size_t)l * 3 * 16384;
        _Float16* wvf_l = wvf + (size_t)l * 3 * 16384;
        _Float16* wqf_l = wqf + (size_t)l * 2 * 16384;
        _Float16* waf_l = waf + (size_t)l * 2 * 16384;
        float* bke_l = bke + (size_t)l * 384;
        float* bve_l = bve + (size_t)l * 384;

        // q projections (fp16 out). Layer 0 reads fp32 inputs and dual-writes the fp16
        // x16 side-channel; layer 1 reads the fp16 activations directly.
        if (l == 0) {
            gemm_v7<1, false, false, false, true, false, true><<<GU1, 256, 0, stream>>>(
                x_user, wqf_l, nullptr, bq + (size_t)0 * 128, nullptr,
                q_user, nullptr, 128, NUSER, nullptr, nullptr, x16u);
            gemm_v7<1, false, false, false, true, false, true><<<gbN, 256, 0, stream>>>(
                x_news, wqf_l + 16384, nullptr, bq + (size_t)1 * 128, nullptr,
                q_news, nullptr, 128, NNEWS, nullptr, nullptr, x16n);
        } else {
            gemm_v7<1, true, false, false, true, false, false><<<GU1, 256, 0, stream>>>(
                x16u, wqf_l, nullptr, bq + (size_t)2 * 128, nullptr,
                q_user, nullptr, 128, NUSER, nullptr, nullptr, nullptr);
            gemm_v7<1, true, false, false, true, false, false><<<gbN, 256, 0, stream>>>(
                x16n, wqf_l + 16384, nullptr, bq + (size_t)3 * 128, nullptr,
                q_news, nullptr, 128, NNEWS, nullptr, nullptr, nullptr);
        }

        // rel0 K/V (user src) -> kv_big, then news attention
        gemm_v7<2, true, false, false, true, false, false><<<GU2, 256, 0, stream>>>(
            x16u, wkf_l, wvf_l, bke_l, bve_l,
            kv_big, kv_big + 128, 256, NUSER, nullptr, nullptr, nullptr);
        attn_v7<0><<<(NNEWS + 15) / 16, 256, 0, stream>>>(
            q_news, kv_big, rp0, nullptr, nullptr, cl, agg_n, NNEWS);

        // rel1 K/V (news src) -> kv_sm ; rel2 K/V (user src) -> kv_big (reuse, stream-ordered)
        gemm_v7<2, true, false, false, true, false, false><<<gbN, 256, 0, stream>>>(
            x16n, wkf_l + 16384, wvf_l + 16384, bke_l + 128, bve_l + 128,
            kv_sm, kv_sm + 128, 256, NNEWS, nullptr, nullptr, nullptr);
        gemm_v7<2, true, false, false, true, false, false><<<GU2, 256, 0, stream>>>(
            x16u, wkf_l + 32768, wvf_l + 32768, bke_l + 256, bve_l + 256,
            kv_big, kv_big + 128, 256, NUSER, nullptr, nullptr, nullptr);
        attn_v7<1><<<2048, 256, 0, stream>>>(
            q_user, kv_sm, rp1, kv_big, rp2, cl, agg_u, NUSER);

        // output transform: relu(sig(skip)*(gelu_agg@Wa + ba) + (1-sig)*x)
        // Layer 0: Xold = x16, write fp16 IN-PLACE into x16. Layer 1: write fp32 d_out.
        if (l == 0) {
            gemm_v7<1, true, false, true, true, true, false><<<GU1, 256, 0, stream>>>(
                agg_u, waf_l, nullptr, ba + (size_t)0 * 128, nullptr,
                x16u, nullptr, 128, NUSER, skip + 0, x16u, nullptr);
            gemm_v7<1, true, false, true, true, true, false><<<gbN, 256, 0, stream>>>(
                agg_n, waf_l + 16384, nullptr, ba + (size_t)1 * 128, nullptr,
                x16n, nullptr, 128, NNEWS, skip + 1, x16n, nullptr);
        } else {
            gemm_v7<1, true, false, true, false, true, false><<<GU1, 256, 0, stream>>>(
                agg_u, waf_l, nullptr, ba + (size_t)2 * 128, nullptr,
                out_user, nullptr, 128, NUSER, skip + 2, x16u, nullptr);
            gemm_v7<1, true, false, true, false, true, false><<<gbN, 256, 0, stream>>>(
                agg_n, waf_l + 16384, nullptr, ba + (size_t)3 * 128, nullptr,
                out_news, nullptr, 128, NNEWS, skip + 3, x16n, nullptr);
        }
    }
    (void)in_sizes; (void)n_in; (void)out_size; (void)ws_size;
}

// Round 6
// 588.209 us; speedup vs baseline: 1.1249x; 1.1249x over previous
//
#include <hip/hip_runtime.h>
#include <cmath>

// ---------------- problem constants ----------------
constexpr int NUSER = 100000;
constexpr int NNEWS = 20000;
constexpr int CH    = 128;
constexpr int NE    = 250000;
constexpr int NTOT  = NNEWS + NUSER + NUSER;   // joint counter array (rel0|rel1|rel2)
constexpr int NSB   = (NTOT + 255) / 256;      // scan blocks = 860

typedef _Float16 f16x8 __attribute__((ext_vector_type(8)));
typedef _Float16 f16x4 __attribute__((ext_vector_type(4)));
typedef _Float16 f16x2 __attribute__((ext_vector_type(2)));
typedef float    f32x4 __attribute__((ext_vector_type(4)));

// ---------------- workspace layout (float units) ----------------
constexpr size_t OFF_QU  = 0;                                   // q_user fp16 [NUSER*128]
constexpr size_t OFF_QN  = OFF_QU  + (size_t)NUSER * 64;        // q_news fp16
constexpr size_t OFF_AGU = OFF_QN  + (size_t)NNEWS * 64;        // agg_user fp16 (gelu'd)
constexpr size_t OFF_AGN = OFF_AGU + (size_t)NUSER * 64;        // agg_news fp16 (gelu'd)
constexpr size_t OFF_KVB = OFF_AGN + (size_t)NNEWS * 64;        // kv_big fp16 [NUSER][256] (k|v interleaved)
constexpr size_t OFF_KVS = OFF_KVB + (size_t)NUSER * 128;       // kv_sm  fp16 [NNEWS][256]
constexpr size_t OFF_WF  = OFF_KVS + (size_t)NNEWS * 128;       // swizzled fp16 frags, BOTH layers (20 matrices)
constexpr size_t OFF_BE  = OFF_WF  + 20 * 8192;                 // bke[2][3][128] + bve[2][3][128] f32
constexpr size_t OFF_INT = OFF_BE  + 2 * 768;
// int offsets (relative, units: int)
constexpr size_t IO_CU   = 0;                    // joint counters [NTOT]
constexpr size_t IO_JRP  = IO_CU  + NTOT;        // joint row_ptr [NTOT+1]
constexpr size_t IO_BSUM = IO_JRP + NTOT + 1;    // scan partials [NSB]
constexpr size_t IO_BOFF = IO_BSUM + NSB;        // scan offsets  [NSB]
constexpr size_t IO_CL   = IO_BOFF + NSB;        // col (src per CSR slot) [3*NE]
constexpr size_t IO_RANK = IO_CL + 3 * NE;       // per-edge rank within dst [3*NE]
constexpr size_t IO_END  = IO_RANK + 3 * NE;
// fp16 activation side-channel (R2: GEMMs are bytes-bound; fp32 x was read 3-4x/layer)
constexpr size_t OFF_X16U = OFF_INT + IO_END;                   // x16 user fp16 [NUSER*128]
constexpr size_t OFF_X16N = OFF_X16U + (size_t)NUSER * 64;      // x16 news fp16

__device__ __forceinline__ float gelu_f(float x) {
    return 0.5f * x * (1.0f + erff(x * 0.70710678118654752440f));
}

// ---------------- swizzled-fragment dest index ----------------
// MFMA 16x16x32 fragment (lane,j): idx = lane&15, k = (lane>>4)*8 + j.
// Wf layout: [kt][ct][lane][j] contiguous -> coalesced b128 stage, conflict-free ds_read_b128.
__device__ __forceinline__ int frag_dest(int k, int col) {
    int kt = k >> 5, quad = (k >> 3) & 3, j = k & 7;
    int ct = col >> 4, m = col & 15;
    int lane = quad * 16 + m;
    return ((kt * 8 + ct) * 64 + lane) * 8 + j;
}

// ---------------- flat weight prep (both layers) + counter zeroing, one dispatch ----------------
constexpr int NEFF = 2 * 2 * 3 * 16384;   // 196608
constexpr int NCVT = 2 * 4 * 16384;       // 131072
constexpr int NBIA = 2 * 2 * 3 * 128;     // 1536
constexpr int NPREP = NEFF + NCVT + NBIA;

__global__ __launch_bounds__(256) void prep_weights_kernel(
    const float* __restrict__ Wk, const float* __restrict__ bk,
    const float* __restrict__ Wv, const float* __restrict__ bv,
    const float* __restrict__ Wq, const float* __restrict__ Wa,
    const float* __restrict__ a_rel, const float* __restrict__ m_rel,
    const float* __restrict__ p_rel,
    _Float16* __restrict__ wkf, float* __restrict__ bke,
    _Float16* __restrict__ wvf, float* __restrict__ bve,
    _Float16* __restrict__ wqf, _Float16* __restrict__ waf,
    int* __restrict__ cu)
{
    const float kscale = 0.17677669529663688f * 1.44269504088896340f;  // 1/sqrt(32)*log2(e)
    int idx = blockIdx.x * 256 + threadIdx.x;
    if (idx < NEFF) {
        int o = idx & 16383;
        int g = idx >> 14;          // (l*2+kind)*3 + r
        int r = g % 3, lk = g / 3, kind = lk & 1, l = lk >> 1;
        int st = (r == 1) ? 1 : 0;
        const float* W   = (kind ? Wv : Wk) + ((size_t)(l * 2 + st)) * 16384;
        const float* rel = (kind ? m_rel : a_rel) + ((size_t)(l * 3 + r)) * 4096;
        _Float16* Wf = (kind ? wvf : wkf) + ((size_t)(l * 3 + r)) * 16384;
        int k = o >> 7, col = o & 127, h = col >> 5, e = col & 31;
        const float* wrow = W + (size_t)k * 128 + h * 32;
        const float* rcol = rel + h * 1024 + e;
        float s = 0.f;
        #pragma unroll
        for (int d = 0; d < 32; ++d) s += wrow[d] * rcol[d * 32];
        if (kind == 0) s *= p_rel[(l * 3 + r) * 4 + h] * kscale;
        Wf[frag_dest(k, col)] = (_Float16)s;
    } else if (idx < NEFF + NCVT) {
        int t = idx - NEFF;
        int o = t & 16383;
        int b = t >> 14;            // l*4 + sub  (sub 0,1: Wq types; 2,3: Wa types)
        int l = b >> 2, sub = b & 3;
        const float* W;
        _Float16* Wf;
        if (sub < 2) { W = Wq + ((size_t)(l * 2 + sub)) * 16384;     Wf = wqf + ((size_t)(l * 2 + sub)) * 16384; }
        else         { W = Wa + ((size_t)(l * 2 + sub - 2)) * 16384; Wf = waf + ((size_t)(l * 2 + sub - 2)) * 16384; }
        int k = o >> 7, col = o & 127;
        Wf[frag_dest(k, col)] = (_Float16)W[o];
    } else if (idx < NPREP) {
        int t = idx - NEFF - NCVT;
        int col = t & 127;
        int g = t >> 7;
        int r = g % 3, lk = g / 3, kind = lk & 1, l = lk >> 1;
        int st = (r == 1) ? 1 : 0;
        const float* bi  = (kind ? bv : bk) + ((size_t)(l * 2 + st)) * 128;
        const float* rel = (kind ? m_rel : a_rel) + ((size_t)(l * 3 + r)) * 4096;
        float* be = (kind ? bve : bke) + (size_t)l * 384 + r * 128;
        int h = col >> 5, e = col & 31;
        float s = 0.f;
        #pragma unroll
        for (int d = 0; d < 32; ++d) s += bi[h * 32 + d] * rel[h * 1024 + d * 32 + e];
        if (kind == 0) s *= p_rel[(l * 3 + r) * 4 + h] * kscale;
        be[col] = s;
    } else if (idx < NPREP + NTOT) {
        cu[idx - NPREP] = 0;       // zero the CSR counters (fused: saves a dispatch)
    }
}

// ---------------- CSR build: hist + per-edge rank (atomics), scan, atomic-free fill ----------------
__global__ void histrank_kernel(const int* __restrict__ e0, const int* __restrict__ e1,
                                const int* __restrict__ e2, int* __restrict__ cu,
                                int* __restrict__ rank) {
    int idx = blockIdx.x * 256 + threadIdx.x;
    if (idx >= 3 * NE) return;
    int r = idx / NE, e = idx - r * NE;
    const int* ei = (r == 0) ? e0 : (r == 1) ? e1 : e2;
    int base = (r == 0) ? 0 : (r == 1) ? NNEWS : (NNEWS + NUSER);
    rank[idx] = atomicAdd(&cu[base + ei[NE + e]], 1);
}

__global__ __launch_bounds__(256) void scan_part_kernel(const int* __restrict__ cu,
                                                        int* __restrict__ bsum) {
    int i = blockIdx.x * 256 + threadIdx.x;
    int v = (i < NTOT) ? cu[i] : 0;
    #pragma unroll
    for (int o = 1; o < 64; o <<= 1) v += __shfl_xor(v, o);
    __shared__ int ws_[4];
    if ((threadIdx.x & 63) == 0) ws_[threadIdx.x >> 6] = v;
    __syncthreads();
    if (threadIdx.x == 0) bsum[blockIdx.x] = ws_[0] + ws_[1] + ws_[2] + ws_[3];
}

__global__ __launch_bounds__(1024) void scan_top_kernel(const int* __restrict__ bsum,
                                                        int* __restrict__ boff,
                                                        int* __restrict__ jrp) {
    __shared__ int wsum[16];
    int tid = threadIdx.x, lane = tid & 63, w = tid >> 6;
    int v = (tid < NSB) ? bsum[tid] : 0;
    int x = v;
    #pragma unroll
    for (int o = 1; o < 64; o <<= 1) { int y = __shfl_up(x, o); if (lane >= o) x += y; }
    if (lane == 63) wsum[w] = x;
    __syncthreads();
    if (tid < 16) {
        int t = wsum[tid];
        #pragma unroll
        for (int o = 1; o < 16; o <<= 1) { int y = __shfl_up(t, o); if (tid >= o) t += y; }
        wsum[tid] = t;
    }
    __syncthreads();
    int woff = w ? wsum[w - 1] : 0;
    if (tid < NSB) boff[tid] = woff + x - v;
    if (tid == 0) jrp[NTOT] = 3 * NE;
}

__global__ __launch_bounds__(256) void scan_fin_kernel(const int* __restrict__ cu,
                                                       const int* __restrict__ boff,
                                                       int* __restrict__ jrp) {
    __shared__ int wsum[4];
    int tid = threadIdx.x, lane = tid & 63, w = tid >> 6;
    int i = blockIdx.x * 256 + tid;
    int v = (i < NTOT) ? cu[i] : 0;
    int x = v;
    #pragma unroll
    for (int o = 1; o < 64; o <<= 1) { int y = __shfl_up(x, o); if (lane >= o) x += y; }
    if (lane == 63) wsum[w] = x;
    __syncthreads();
    int woff = 0;
    #pragma unroll
    for (int k = 0; k < 4; ++k) if (k < w) woff += wsum[k];
    int excl = boff[blockIdx.x] + woff + x - v;
    if (i < NTOT) jrp[i] = excl;
}

__global__ void fill_kernel(const int* __restrict__ e0, const int* __restrict__ e1,
                            const int* __restrict__ e2, const int* __restrict__ jrp,
                            const int* __restrict__ rank, int* __restrict__ cl) {
    int idx = blockIdx.x * 256 + threadIdx.x;
    if (idx >= 3 * NE) return;
    int r = idx / NE, e = idx - r * NE;
    const int* ei = (r == 0) ? e0 : (r == 1) ? e1 : e2;
    int base = (r == 0) ? 0 : (r == 1) ? NNEWS : (NNEWS + NUSER);
    int dst = ei[NE + e], src = ei[e];
    cl[jrp[base + dst] + rank[idx]] = src;   // no atomics (R8: fill3 = 46 us of atomic latency)
}

// ---------------- MFMA GEMM v8: v6 (R3-best) + LDS-coalesced fp16 epilogue ----------------
// R5 theory: fp16 epilogue stores were f16x4 (8B) per lane -> each store instruction hits
// 16 disjoint 32B segments (stride 512B for kv): partial-line HBM writes + 16 transactions
// per instruction. v8 stages the tile output through a 16KB XOR-swizzled LDS buffer
// (byte ^= (row&7)<<4, 8B/16B granularity preserved) and stores 256-thread-contiguous
// f16x8 chunks -> >=256B contiguous runs. LDS: NOUT2 80KB (still 2 blocks/CU), NOUT1 48KB.
// fp32 output path (epi l1) already stores 64B segments -> kept direct.
template<int NOUT, int T, bool IN_HALF, bool GELU_IN, bool SKIP_OUT, bool OUT_HALF,
         bool XOLD_HALF, bool WRITE_X16>
__global__ __launch_bounds__(256) void gemm_v8(
    const void* __restrict__ Ain,
    const _Float16* __restrict__ Wf0, const _Float16* __restrict__ Wf1,
    const float* __restrict__ b0, const float* __restrict__ b1,
    void* out0, void* out1, int ostride,
    int N, const float* __restrict__ skipv, const void* Xold,
    _Float16* x16out)
{
    __shared__ _Float16 sW[NOUT * 16384];            // 32 KB per weight matrix
    __shared__ _Float16 sE[OUT_HALF ? 8192 : 64];    // 16 KB epilogue transpose buffer
    const int tid = threadIdx.x;
    const int lane = tid & 63;
    const int m = lane & 15, quad = lane >> 4, wave = tid >> 6;
    const int base_row = blockIdx.x * T * 64;

    // named double buffers (never runtime-indexed -> stay in VGPRs)
    f32x4 xc32_0, xc32_1, xc32_2, xc32_3, xc32_4, xc32_5, xc32_6, xc32_7;
    f32x4 xn32_0, xn32_1, xn32_2, xn32_3, xn32_4, xn32_5, xn32_6, xn32_7;
    f16x8 xc16_0, xc16_1, xc16_2, xc16_3;
    f16x8 xn16_0, xn16_1, xn16_2, xn16_3;

#define LOADX_NEXT(tt)                                                              \
    do {                                                                            \
        int node_ = base_row + (tt) * 64 + wave * 16 + m;                           \
        if (node_ > N - 1) node_ = N - 1;                                           \
        if constexpr (IN_HALF) {                                                    \
            const _Float16* A_ = (const _Float16*)Ain + (size_t)node_ * 128 + quad * 8; \
            xn16_0 = *(const f16x8*)(A_);                                           \
            xn16_1 = *(const f16x8*)(A_ + 32);                                      \
            xn16_2 = *(const f16x8*)(A_ + 64);                                      \
            xn16_3 = *(const f16x8*)(A_ + 96);                                      \
        } else {                                                                    \
            const float* A_ = (const float*)Ain + (size_t)node_ * 128 + quad * 8;   \
            xn32_0 = *(const f32x4*)(A_);        xn32_1 = *(const f32x4*)(A_ + 4);  \
            xn32_2 = *(const f32x4*)(A_ + 32);   xn32_3 = *(const f32x4*)(A_ + 36); \
            xn32_4 = *(const f32x4*)(A_ + 64);   xn32_5 = *(const f32x4*)(A_ + 68); \
            xn32_6 = *(const f32x4*)(A_ + 96);   xn32_7 = *(const f32x4*)(A_ + 100);\
        }                                                                           \
    } while (0)

#define ROTATE_X()                                                                  \
    do {                                                                            \
        if constexpr (IN_HALF) {                                                    \
            xc16_0 = xn16_0; xc16_1 = xn16_1; xc16_2 = xn16_2; xc16_3 = xn16_3;     \
        } else {                                                                    \
            xc32_0 = xn32_0; xc32_1 = xn32_1; xc32_2 = xn32_2; xc32_3 = xn32_3;     \
            xc32_4 = xn32_4; xc32_5 = xn32_5; xc32_6 = xn32_6; xc32_7 = xn32_7;     \
        }                                                                           \
    } while (0)

    // tile-0 x prefetch, issued before LDS staging so HBM latency hides under it
    LOADX_NEXT(0);
    ROTATE_X();

    for (int i = tid; i < NOUT * 2048; i += 256) {
        const _Float16* src = (NOUT == 1 || i < 2048) ? (Wf0 + (size_t)i * 8)
                                                      : (Wf1 + (size_t)(i - 2048) * 8);
        *(f16x8*)(sW + (size_t)i * 8) = *(const f16x8*)src;
    }
    __syncthreads();

    float aS = 0.f, bSk = 0.f;
    if constexpr (SKIP_OUT) {
        float sv = skipv[0];
        aS = 1.0f / (1.0f + expf(-sv));
        bSk = 1.0f - aS;
    }

    #pragma unroll
    for (int t = 0; t < T; ++t) {
        const int row0 = base_row + t * 64;
        if (row0 >= N) break;                       // block-uniform (barriers below are safe)
        const int node  = row0 + wave * 16 + m;
        const int nodec = (node < N) ? node : (N - 1);

        // issue NEXT tile's x loads before this tile's compute
        if (t + 1 < T) LOADX_NEXT(t + 1);

        // skip-path residual, loaded early so it completes under the MFMAs
        f32x4 xo0, xo1, xo2, xo3, xo4, xo5, xo6, xo7;
        f16x4 xh0, xh1, xh2, xh3, xh4, xh5, xh6, xh7;
        if constexpr (SKIP_OUT) {
            if constexpr (XOLD_HALF) {
                const _Float16* Xo = (const _Float16*)Xold + (size_t)nodec * 128 + quad * 4;
                xh0 = *(const f16x4*)(Xo);        xh1 = *(const f16x4*)(Xo + 16);
                xh2 = *(const f16x4*)(Xo + 32);   xh3 = *(const f16x4*)(Xo + 48);
                xh4 = *(const f16x4*)(Xo + 64);   xh5 = *(const f16x4*)(Xo + 80);
                xh6 = *(const f16x4*)(Xo + 96);   xh7 = *(const f16x4*)(Xo + 112);
            } else {
                const float* Xo = (const float*)Xold + (size_t)nodec * 128 + quad * 4;
                xo0 = *(const f32x4*)(Xo);       xo1 = *(const f32x4*)(Xo + 16);
                xo2 = *(const f32x4*)(Xo + 32);  xo3 = *(const f32x4*)(Xo + 48);
                xo4 = *(const f32x4*)(Xo + 64);  xo5 = *(const f32x4*)(Xo + 80);
                xo6 = *(const f32x4*)(Xo + 96);  xo7 = *(const f32x4*)(Xo + 112);
            }
        }

        // convert current x to MFMA B-frags
        f16x8 xf[4];
        if constexpr (IN_HALF) {
            xf[0] = xc16_0; xf[1] = xc16_1; xf[2] = xc16_2; xf[3] = xc16_3;
            if constexpr (GELU_IN) {
                #pragma unroll
                for (int kt = 0; kt < 4; ++kt)
                    #pragma unroll
                    for (int j = 0; j < 8; ++j) xf[kt][j] = (_Float16)gelu_f((float)xf[kt][j]);
            }
        } else {
            f32x4 a0[4] = {xc32_0, xc32_2, xc32_4, xc32_6};
            f32x4 a1[4] = {xc32_1, xc32_3, xc32_5, xc32_7};
            #pragma unroll
            for (int kt = 0; kt < 4; ++kt) {
                f32x4 u = a0[kt], v = a1[kt];
                if constexpr (GELU_IN) {
                    #pragma unroll
                    for (int j = 0; j < 4; ++j) { u[j] = gelu_f(u[j]); v[j] = gelu_f(v[j]); }
                }
                xf[kt] = (f16x8){(_Float16)u[0], (_Float16)u[1], (_Float16)u[2], (_Float16)u[3],
                                 (_Float16)v[0], (_Float16)v[1], (_Float16)v[2], (_Float16)v[3]};
            }
        }

        // fp16 activation side-channel: persist the converted x (layer-0 q GEMMs).
        // 16B/lane, 64B/node contiguous -> already coalesced, direct store.
        if constexpr (WRITE_X16) {
            if (node < N) {
                _Float16* xd = x16out + (size_t)node * 128 + quad * 8;
                *(f16x8*)(xd)      = xf[0];
                *(f16x8*)(xd + 32) = xf[1];
                *(f16x8*)(xd + 64) = xf[2];
                *(f16x8*)(xd + 96) = xf[3];
            }
        }

        f32x4 acc0[8], acc1[8];
        #pragma unroll
        for (int u = 0; u < 8; ++u) {
            acc0[u] = (f32x4){0.f, 0.f, 0.f, 0.f};
            if constexpr (NOUT > 1) acc1[u] = (f32x4){0.f, 0.f, 0.f, 0.f};
        }

        #pragma unroll
        for (int kt = 0; kt < 4; ++kt) {
            #pragma unroll
            for (int ct = 0; ct < 8; ++ct) {
                f16x8 wf0 = *(const f16x8*)(sW + ((kt * 8 + ct) * 64 + lane) * 8);
                acc0[ct] = __builtin_amdgcn_mfma_f32_16x16x32_f16(wf0, xf[kt], acc0[ct], 0, 0, 0);
                if constexpr (NOUT > 1) {
                    f16x8 wf1 = *(const f16x8*)(sW + 16384 + ((kt * 8 + ct) * 64 + lane) * 8);
                    acc1[ct] = __builtin_amdgcn_mfma_f32_16x16x32_f16(wf1, xf[kt], acc1[ct], 0, 0, 0);
                }
            }
        }

        // gather skip operand (register-form) for the epilogue math
        f32x4 xoa[8];
        if constexpr (SKIP_OUT) {
            if constexpr (XOLD_HALF) {
                f16x4 xhh[8] = {xh0, xh1, xh2, xh3, xh4, xh5, xh6, xh7};
                #pragma unroll
                for (int ct = 0; ct < 8; ++ct)
                    xoa[ct] = (f32x4){(float)xhh[ct][0], (float)xhh[ct][1],
                                      (float)xhh[ct][2], (float)xhh[ct][3]};
            } else {
                xoa[0] = xo0; xoa[1] = xo1; xoa[2] = xo2; xoa[3] = xo3;
                xoa[4] = xo4; xoa[5] = xo5; xoa[6] = xo6; xoa[7] = xo7;
            }
        }

        if constexpr (!OUT_HALF) {
            // fp32 output: f32x4 = 16B/lane, 64B/node contiguous -> direct store fine
            if (node < N) {
                #pragma unroll
                for (int ct = 0; ct < 8; ++ct) {
                    int c = ct * 16 + quad * 4;
                    f32x4 r = acc0[ct] + *(const f32x4*)(b0 + c);
                    if constexpr (SKIP_OUT) {
                        #pragma unroll
                        for (int j = 0; j < 4; ++j) r[j] = fmaxf(aS * r[j] + bSk * xoa[ct][j], 0.f);
                    }
                    *(f32x4*)((float*)out0 + (size_t)node * ostride + c) = r;
                }
            }
        } else {
            // fp16 output: LDS transpose -> coalesced f16x8 stores (>=256B runs)
            const int r16 = wave * 16 + m;            // row within tile (0..63)
            const int swz = (r16 & 7) << 4;           // XOR-swizzle, bits 4-6
            // matrix 0
            {
                f16x4 h[8];
                #pragma unroll
                for (int ct = 0; ct < 8; ++ct) {
                    int c = ct * 16 + quad * 4;
                    f32x4 r = acc0[ct] + *(const f32x4*)(b0 + c);
                    if constexpr (SKIP_OUT) {
                        #pragma unroll
                        for (int j = 0; j < 4; ++j) r[j] = fmaxf(aS * r[j] + bSk * xoa[ct][j], 0.f);
                    }
                    h[ct] = (f16x4){(_Float16)r[0], (_Float16)r[1], (_Float16)r[2], (_Float16)r[3]};
                }
                __syncthreads();                       // prior pass's reads complete
                #pragma unroll
                for (int ct = 0; ct < 8; ++ct)
                    *(f16x4*)((char*)sE + r16 * 256 + ((ct * 32 + quad * 8) ^ swz)) = h[ct];
                __syncthreads();
                #pragma unroll
                for (int j = 0; j < 4; ++j) {
                    int c = j * 256 + tid;             // 0..1023 chunks of 16B
                    int n16 = c >> 4, w = c & 15;
                    f16x8 v = *(const f16x8*)((const char*)sE + n16 * 256 + ((w * 16) ^ ((n16 & 7) << 4)));
                    int gnode = row0 + n16;
                    if (gnode < N)
                        *(f16x8*)((_Float16*)out0 + (size_t)gnode * ostride + w * 8) = v;
                }
            }
            if constexpr (NOUT > 1) {                  // matrix 1 (reuses sE)
                f16x4 h[8];
                #pragma unroll
                for (int ct = 0; ct < 8; ++ct) {
                    int c = ct * 16 + quad * 4;
                    f32x4 r = acc1[ct] + *(const f32x4*)(b1 + c);
                    h[ct] = (f16x4){(_Float16)r[0], (_Float16)r[1], (_Float16)r[2], (_Float16)r[3]};
                }
                __syncthreads();
                #pragma unroll
                for (int ct = 0; ct < 8; ++ct)
                    *(f16x4*)((char*)sE + r16 * 256 + ((ct * 32 + quad * 8) ^ swz)) = h[ct];
                __syncthreads();
                #pragma unroll
                for (int j = 0; j < 4; ++j) {
                    int c = j * 256 + tid;
                    int n16 = c >> 4, w = c & 15;
                    f16x8 v = *(const f16x8*)((const char*)sE + n16 * 256 + ((w * 16) ^ ((n16 & 7) << 4)));
                    int gnode = row0 + n16;
                    if (gnode < N)
                        *(f16x8*)((_Float16*)out1 + (size_t)gnode * ostride + w * 8) = v;
                }
            }
        }

        if (t + 1 < T) ROTATE_X();
    }
#undef LOADX_NEXT
#undef ROTATE_X
}

// ---------------- attention v5 (final: v6 4-slot & v7 merge both regressed) ----------------
// v6: +issue work at 64% VALUBusy; v7: 52 VGPR -> occupancy 54->32%. v5 = 36 VGPR, 48us,
// 3.25 TB/s on a random-512B-gather = near the gather-BW ceiling. Do not touch.
// kv interleaved [node][k|v] fp16. Lane sub (0..15): channels sub*8..+7, head = sub>>2.
// w = exp2(score) (log2e folded into k_eff). agg := gelu(softmax-agg).
__global__ __launch_bounds__(256) void attn_v5(
    const _Float16* __restrict__ q,
    const _Float16* __restrict__ kv1, const int* __restrict__ rp1,
    const _Float16* __restrict__ kv2, const int* __restrict__ rp2,
    const int* __restrict__ cl,
    _Float16* __restrict__ agg, int Ndst, int two)
{
    int d = blockIdx.x * 16 + (threadIdx.x >> 4);   // 16 nodes per block (4 per wave)
    if (d >= Ndst) return;
    const int sub = threadIdx.x & 15;
    f16x8 qh = *(const f16x8*)(q + (size_t)d * 128 + sub * 8);
    float acc[8] = {0.f, 0.f, 0.f, 0.f, 0.f, 0.f, 0.f, 0.f};

    for (int rel = 0; rel < 1 + two; ++rel) {
        const _Float16* kv = rel ? kv2 : kv1;
        const int* rp = rel ? rp2 : rp1;
        int e0 = rp[d], e1 = rp[d + 1];
        float den = 0.f;
        float s[8] = {0.f, 0.f, 0.f, 0.f, 0.f, 0.f, 0.f, 0.f};
        int e = e0;
        for (; e + 1 < e1; e += 2) {                // two independent chains per iter
            int s0 = cl[e], s1 = cl[e + 1];
            const _Float16* r0 = kv + (size_t)s0 * 256;
            const _Float16* r1 = kv + (size_t)s1 * 256;
            f16x8 k0 = *(const f16x8*)(r0 + sub * 8);
            f16x8 v0 = *(const f16x8*)(r0 + 128 + sub * 8);
            f16x8 k1 = *(const f16x8*)(r1 + sub * 8);
            f16x8 v1 = *(const f16x8*)(r1 + 128 + sub * 8);
            float p0 = 0.f, p1 = 0.f;
#if __has_builtin(__builtin_amdgcn_fdot2)
            const f16x2* qp = (const f16x2*)&qh;
            const f16x2* a0 = (const f16x2*)&k0;
            const f16x2* a1 = (const f16x2*)&k1;
            #pragma unroll
            for (int j = 0; j < 4; ++j) {
                p0 = __builtin_amdgcn_fdot2(a0[j], qp[j], p0, false);
                p1 = __builtin_amdgcn_fdot2(a1[j], qp[j], p1, false);
            }
#else
            #pragma unroll
            for (int j = 0; j < 8; ++j) {
                p0 += (float)k0[j] * (float)qh[j];
                p1 += (float)k1[j] * (float)qh[j];
            }
#endif
            p0 += __shfl_xor(p0, 1); p1 += __shfl_xor(p1, 1);
            p0 += __shfl_xor(p0, 2); p1 += __shfl_xor(p1, 2);
            float w0 = exp2f(p0), w1 = exp2f(p1);
            den += w0 + w1;
            #pragma unroll
            for (int j = 0; j < 8; ++j) s[j] += w0 * (float)v0[j] + w1 * (float)v1[j];
        }
        if (e < e1) {
            int s0 = cl[e];
            const _Float16* r0 = kv + (size_t)s0 * 256;
            f16x8 k0 = *(const f16x8*)(r0 + sub * 8);
            f16x8 v0 = *(const f16x8*)(r0 + 128 + sub * 8);
            float p0 = 0.f;
#if __has_builtin(__builtin_amdgcn_fdot2)
            const f16x2* qp = (const f16x2*)&qh;
            const f16x2* a0 = (const f16x2*)&k0;
            #pragma unroll
            for (int j = 0; j < 4; ++j) p0 = __builtin_amdgcn_fdot2(a0[j], qp[j], p0, false);
#else
            #pragma unroll
            for (int j = 0; j < 8; ++j) p0 += (float)k0[j] * (float)qh[j];
#endif
            p0 += __shfl_xor(p0, 1);
            p0 += __shfl_xor(p0, 2);
            float w0 = exp2f(p0);
            den += w0;
            #pragma unroll
            for (int j = 0; j < 8; ++j) s[j] += w0 * (float)v0[j];
        }
        if (den > 0.f) {
            float inv = 1.f / den;
            #pragma unroll
            for (int j = 0; j < 8; ++j) acc[j] += s[j] * inv;
        }
    }

    f16x8 o;
    #pragma unroll
    for (int j = 0; j < 8; ++j) o[j] = (_Float16)gelu_f(acc[j]);   // gelu fused
    *(f16x8*)(agg + (size_t)d * 128 + sub * 8) = o;
}

// ---------------- orchestration (R3 structure) ----------------
extern "C" void kernel_launch(void* const* d_in, const int* in_sizes, int n_in,
                              void* d_out, int out_size, void* d_ws, size_t ws_size,
                              hipStream_t stream)
{
    const float* x_user = (const float*)d_in[0];
    const float* x_news = (const float*)d_in[1];
    const int* ei0 = (const int*)d_in[2];
    const int* ei1 = (const int*)d_in[3];
    const int* ei2 = (const int*)d_in[4];
    const float* Wk = (const float*)d_in[5];
    const float* bk = (const float*)d_in[6];
    const float* Wq = (const float*)d_in[7];
    const float* bq = (const float*)d_in[8];
    const float* Wv = (const float*)d_in[9];
    const float* bv = (const float*)d_in[10];
    const float* Wa = (const float*)d_in[11];
    const float* ba = (const float*)d_in[12];
    const float* skip = (const float*)d_in[13];
    const float* a_rel = (const float*)d_in[14];
    const float* m_rel = (const float*)d_in[15];
    const float* p_rel = (const float*)d_in[16];

    float* ws = (float*)d_ws;
    _Float16* q_user  = (_Float16*)(ws + OFF_QU);
    _Float16* q_news  = (_Float16*)(ws + OFF_QN);
    _Float16* agg_u   = (_Float16*)(ws + OFF_AGU);
    _Float16* agg_n   = (_Float16*)(ws + OFF_AGN);
    _Float16* kv_big  = (_Float16*)(ws + OFF_KVB);
    _Float16* kv_sm   = (_Float16*)(ws + OFF_KVS);
    _Float16* wkf = (_Float16*)(ws + OFF_WF);       // [2][3] matrices
    _Float16* wvf = wkf + 6 * 16384;                // [2][3]
    _Float16* wqf = wvf + 6 * 16384;                // [2][2]
    _Float16* waf = wqf + 4 * 16384;                // [2][2]
    float* bke = ws + OFF_BE;                       // [2][3][128]
    float* bve = bke + 768;
    int* ib   = (int*)(ws + OFF_INT);
    int* cu   = ib + IO_CU;
    int* jrp  = ib + IO_JRP;
    int* bsum = ib + IO_BSUM;
    int* boff = ib + IO_BOFF;
    int* cl   = ib + IO_CL;
    int* rank = ib + IO_RANK;
    _Float16* x16u = (_Float16*)(ws + OFF_X16U);    // fp16 activation side-channel
    _Float16* x16n = (_Float16*)(ws + OFF_X16N);
    const int* rp0 = jrp;
    const int* rp1 = jrp + NNEWS;
    const int* rp2 = jrp + NNEWS + NUSER;

    // ---- weight prep (both layers) + counter zero, one flat dispatch ----
    prep_weights_kernel<<<(NPREP + NTOT + 255) / 256, 256, 0, stream>>>(
        Wk, bk, Wv, bv, Wq, Wa, a_rel, m_rel, p_rel,
        wkf, bke, wvf, bve, wqf, waf, cu);

    // ---- CSR build: hist+rank (atomics) -> scan -> atomic-free fill ----
    int g3e = (3 * NE + 255) / 256;
    histrank_kernel<<<g3e, 256, 0, stream>>>(ei0, ei1, ei2, cu, rank);
    scan_part_kernel<<<NSB, 256, 0, stream>>>(cu, bsum);
    scan_top_kernel<<<1, 1024, 0, stream>>>(bsum, boff, jrp);
    scan_fin_kernel<<<NSB, 256, 0, stream>>>(cu, boff, jrp);
    fill_kernel<<<g3e, 256, 0, stream>>>(ei0, ei1, ei2, jrp, rank, cl);

    float* out_user = (float*)d_out;
    float* out_news = (float*)d_out + (size_t)NUSER * CH;

    constexpr int T1 = 2;   // NOUT=1 user GEMMs
    constexpr int T2 = 4;   // NOUT=2 user GEMMs (80KB LDS -> 2 blocks/CU)
    int gbU1 = (NUSER + 64 * T1 - 1) / (64 * T1);
    int gbU2 = (NUSER + 64 * T2 - 1) / (64 * T2);
    int gbN  = (NNEWS + 63) / 64;                  // news: T=1 (keep TLP)

    for (int l = 0; l < 2; ++l) {
        _Float16* wkf_l = wkf + (size_t)l * 3 * 16384;
        _Float16* wvf_l = wvf + (size_t)l * 3 * 16384;
        _Float16* wqf_l = wqf + (size_t)l * 2 * 16384;
        _Float16* waf_l = waf + (size_t)l * 2 * 16384;
        float* bke_l = bke + (size_t)l * 384;
        float* bve_l = bve + (size_t)l * 384;

        // q projections (fp16 out). Layer 0 reads fp32 inputs and dual-writes the fp16
        // x16 side-channel; layer 1 reads the fp16 activations directly.
        if (l == 0) {
            gemm_v8<1, T1, false, false, false, true, false, true><<<gbU1, 256, 0, stream>>>(
                x_user, wqf_l, nullptr, bq + (size_t)0 * 128, nullptr,
                q_user, nullptr, 128, NUSER, nullptr, nullptr, x16u);
            gemm_v8<1, 1, false, false, false, true, false, true><<<gbN, 256, 0, stream>>>(
                x_news, wqf_l + 16384, nullptr, bq + (size_t)1 * 128, nullptr,
                q_news, nullptr, 128, NNEWS, nullptr, nullptr, x16n);
        } else {
            gemm_v8<1, T1, true, false, false, true, false, false><<<gbU1, 256, 0, stream>>>(
                x16u, wqf_l, nullptr, bq + (size_t)2 * 128, nullptr,
                q_user, nullptr, 128, NUSER, nullptr, nullptr, nullptr);
            gemm_v8<1, 1, true, false, false, true, false, false><<<gbN, 256, 0, stream>>>(
                x16n, wqf_l + 16384, nullptr, bq + (size_t)3 * 128, nullptr,
                q_news, nullptr, 128, NNEWS, nullptr, nullptr, nullptr);
        }

        // rel0 K/V (user src) -> kv_big, then news attention
        gemm_v8<2, T2, true, false, false, true, false, false><<<gbU2, 256, 0, stream>>>(
            x16u, wkf_l, wvf_l, bke_l, bve_l,
            kv_big, kv_big + 128, 256, NUSER, nullptr, nullptr, nullptr);
        attn_v5<<<(NNEWS + 15) / 16, 256, 0, stream>>>(
            q_news, kv_big, rp0, nullptr, nullptr, cl, agg_n, NNEWS, 0);

        // rel1 K/V (news src) -> kv_sm ; rel2 K/V (user src) -> kv_big (reuse, stream-ordered)
        gemm_v8<2, 1, true, false, false, true, false, false><<<gbN, 256, 0, stream>>>(
            x16n, wkf_l + 16384, wvf_l + 16384, bke_l + 128, bve_l + 128,
            kv_sm, kv_sm + 128, 256, NNEWS, nullptr, nullptr, nullptr);
        gemm_v8<2, T2, true, false, false, true, false, false><<<gbU2, 256, 0, stream>>>(
            x16u, wkf_l + 32768, wvf_l + 32768, bke_l + 256, bve_l + 256,
            kv_big, kv_big + 128, 256, NUSER, nullptr, nullptr, nullptr);
        attn_v5<<<(NUSER + 15) / 16, 256, 0, stream>>>(
            q_user, kv_sm, rp1, kv_big, rp2, cl, agg_u, NUSER, 1);

        // output transform: relu(sig(skip)*(gelu_agg@Wa + ba) + (1-sig)*x)
        // Layer 0: Xold = x16, write fp16 IN-PLACE into x16. Layer 1: write fp32 d_out.
        if (l == 0) {
            gemm_v8<1, T1, true, false, true, true, true, false><<<gbU1, 256, 0, stream>>>(
                agg_u, waf_l, nullptr, ba + (size_t)0 * 128, nullptr,
                x16u, nullptr, 128, NUSER, skip + 0, x16u, nullptr);
            gemm_v8<1, 1, true, false, true, true, true, false><<<gbN, 256, 0, stream>>>(
                agg_n, waf_l + 16384, nullptr, ba + (size_t)1 * 128, nullptr,
                x16n, nullptr, 128, NNEWS, skip + 1, x16n, nullptr);
        } else {
            gemm_v8<1, T1, true, false, true, false, true, false><<<gbU1, 256, 0, stream>>>(
                agg_u, waf_l, nullptr, ba + (size_t)2 * 128, nullptr,
                out_user, nullptr, 128, NUSER, skip + 2, x16u, nullptr);
            gemm_v8<1, 1, true, false, true, false, true, false><<<gbN, 256, 0, stream>>>(
                agg_n, waf_l + 16384, nullptr, ba + (size_t)3 * 128, nullptr,
                out_news, nullptr, 128, NNEWS, skip + 3, x16n, nullptr);
        }
    }
    (void)in_sizes; (void)n_in; (void)out_size; (void)ws_size;
}

// Round 7
// 481.402 us; speedup vs baseline: 1.3745x; 1.2219x over previous
//
#include <hip/hip_runtime.h>
#include <cmath>

// ---------------- problem constants ----------------
constexpr int NUSER = 100000;
constexpr int NNEWS = 20000;
constexpr int CH    = 128;
constexpr int NE    = 250000;
constexpr int NTOT  = NNEWS + NUSER + NUSER;   // joint counter array (rel0|rel1|rel2)
constexpr int NSB   = (NTOT + 255) / 256;      // scan blocks = 860

typedef _Float16 f16x8 __attribute__((ext_vector_type(8)));
typedef _Float16 f16x4 __attribute__((ext_vector_type(4)));
typedef _Float16 f16x2 __attribute__((ext_vector_type(2)));
typedef float    f32x4 __attribute__((ext_vector_type(4)));

// ---------------- workspace layout (float units) ----------------
constexpr size_t OFF_QU  = 0;                                   // q_user fp16 [NUSER*128]
constexpr size_t OFF_QN  = OFF_QU  + (size_t)NUSER * 64;        // q_news fp16
constexpr size_t OFF_AGU = OFF_QN  + (size_t)NNEWS * 64;        // agg_user fp16 (gelu'd)
constexpr size_t OFF_AGN = OFF_AGU + (size_t)NUSER * 64;        // agg_news fp16 (gelu'd)
constexpr size_t OFF_KVB = OFF_AGN + (size_t)NNEWS * 64;        // kv_big fp16 [NUSER][256] (k|v interleaved)
constexpr size_t OFF_KVS = OFF_KVB + (size_t)NUSER * 128;       // kv_sm  fp16 [NNEWS][256]
constexpr size_t OFF_WF  = OFF_KVS + (size_t)NNEWS * 128;       // swizzled fp16 frags, BOTH layers (20 matrices)
constexpr size_t OFF_BE  = OFF_WF  + 20 * 8192;                 // bke[2][3][128] + bve[2][3][128] f32
constexpr size_t OFF_INT = OFF_BE  + 2 * 768;
// int offsets (relative, units: int)
constexpr size_t IO_CU   = 0;                    // joint counters [NTOT]
constexpr size_t IO_JRP  = IO_CU  + NTOT;        // joint row_ptr [NTOT+1]
constexpr size_t IO_BSUM = IO_JRP + NTOT + 1;    // scan partials [NSB]
constexpr size_t IO_BOFF = IO_BSUM + NSB;        // scan offsets  [NSB]
constexpr size_t IO_CL   = IO_BOFF + NSB;        // col (src per CSR slot) [3*NE]
constexpr size_t IO_RANK = IO_CL + 3 * NE;       // per-edge rank within dst [3*NE]
constexpr size_t IO_END  = IO_RANK + 3 * NE;
// fp16 activation side-channel (R2: GEMMs bytes-bound; fp32 x was read 3-4x/layer)
constexpr size_t OFF_X16U = OFF_INT + IO_END;                   // x16 user fp16 [NUSER*128]
constexpr size_t OFF_X16N = OFF_X16U + (size_t)NUSER * 64;      // x16 news fp16
// R7: second big KV buffer decouples kv2 from attn_news -> all 5 projection GEMMs fuse.
constexpr size_t OFF_KVB2 = OFF_X16N + (size_t)NNEWS * 64;      // kv_big2 fp16 [NUSER][256]
constexpr size_t WS_NEED_ROOMY = (OFF_KVB2 + (size_t)NUSER * 128) * sizeof(float);

__device__ __forceinline__ float gelu_f(float x) {
    return 0.5f * x * (1.0f + erff(x * 0.70710678118654752440f));
}

// ---------------- swizzled-fragment dest index ----------------
__device__ __forceinline__ int frag_dest(int k, int col) {
    int kt = k >> 5, quad = (k >> 3) & 3, j = k & 7;
    int ct = col >> 4, m = col & 15;
    int lane = quad * 16 + m;
    return ((kt * 8 + ct) * 64 + lane) * 8 + j;
}

// ---------------- flat weight prep (both layers) + counter zeroing, one dispatch ----------------
constexpr int NEFF = 2 * 2 * 3 * 16384;   // 196608
constexpr int NCVT = 2 * 4 * 16384;       // 131072
constexpr int NBIA = 2 * 2 * 3 * 128;     // 1536
constexpr int NPREP = NEFF + NCVT + NBIA;

__global__ __launch_bounds__(256) void prep_weights_kernel(
    const float* __restrict__ Wk, const float* __restrict__ bk,
    const float* __restrict__ Wv, const float* __restrict__ bv,
    const float* __restrict__ Wq, const float* __restrict__ Wa,
    const float* __restrict__ a_rel, const float* __restrict__ m_rel,
    const float* __restrict__ p_rel,
    _Float16* __restrict__ wkf, float* __restrict__ bke,
    _Float16* __restrict__ wvf, float* __restrict__ bve,
    _Float16* __restrict__ wqf, _Float16* __restrict__ waf,
    int* __restrict__ cu)
{
    const float kscale = 0.17677669529663688f * 1.44269504088896340f;  // 1/sqrt(32)*log2(e)
    int idx = blockIdx.x * 256 + threadIdx.x;
    if (idx < NEFF) {
        int o = idx & 16383;
        int g = idx >> 14;          // (l*2+kind)*3 + r
        int r = g % 3, lk = g / 3, kind = lk & 1, l = lk >> 1;
        int st = (r == 1) ? 1 : 0;
        const float* W   = (kind ? Wv : Wk) + ((size_t)(l * 2 + st)) * 16384;
        const float* rel = (kind ? m_rel : a_rel) + ((size_t)(l * 3 + r)) * 4096;
        _Float16* Wf = (kind ? wvf : wkf) + ((size_t)(l * 3 + r)) * 16384;
        int k = o >> 7, col = o & 127, h = col >> 5, e = col & 31;
        const float* wrow = W + (size_t)k * 128 + h * 32;
        const float* rcol = rel + h * 1024 + e;
        float s = 0.f;
        #pragma unroll
        for (int d = 0; d < 32; ++d) s += wrow[d] * rcol[d * 32];
        if (kind == 0) s *= p_rel[(l * 3 + r) * 4 + h] * kscale;
        Wf[frag_dest(k, col)] = (_Float16)s;
    } else if (idx < NEFF + NCVT) {
        int t = idx - NEFF;
        int o = t & 16383;
        int b = t >> 14;            // l*4 + sub  (sub 0,1: Wq types; 2,3: Wa types)
        int l = b >> 2, sub = b & 3;
        const float* W;
        _Float16* Wf;
        if (sub < 2) { W = Wq + ((size_t)(l * 2 + sub)) * 16384;     Wf = wqf + ((size_t)(l * 2 + sub)) * 16384; }
        else         { W = Wa + ((size_t)(l * 2 + sub - 2)) * 16384; Wf = waf + ((size_t)(l * 2 + sub - 2)) * 16384; }
        int k = o >> 7, col = o & 127;
        Wf[frag_dest(k, col)] = (_Float16)W[o];
    } else if (idx < NPREP) {
        int t = idx - NEFF - NCVT;
        int col = t & 127;
        int g = t >> 7;
        int r = g % 3, lk = g / 3, kind = lk & 1, l = lk >> 1;
        int st = (r == 1) ? 1 : 0;
        const float* bi  = (kind ? bv : bk) + ((size_t)(l * 2 + st)) * 128;
        const float* rel = (kind ? m_rel : a_rel) + ((size_t)(l * 3 + r)) * 4096;
        float* be = (kind ? bve : bke) + (size_t)l * 384 + r * 128;
        int h = col >> 5, e = col & 31;
        float s = 0.f;
        #pragma unroll
        for (int d = 0; d < 32; ++d) s += bi[h * 32 + d] * rel[h * 1024 + d * 32 + e];
        if (kind == 0) s *= p_rel[(l * 3 + r) * 4 + h] * kscale;
        be[col] = s;
    } else if (idx < NPREP + NTOT) {
        cu[idx - NPREP] = 0;       // zero the CSR counters
    }
}

// ---------------- CSR build: hist + per-edge rank (atomics), scan, atomic-free fill ----------------
__global__ void histrank_kernel(const int* __restrict__ e0, const int* __restrict__ e1,
                                const int* __restrict__ e2, int* __restrict__ cu,
                                int* __restrict__ rank) {
    int idx = blockIdx.x * 256 + threadIdx.x;
    if (idx >= 3 * NE) return;
    int r = idx / NE, e = idx - r * NE;
    const int* ei = (r == 0) ? e0 : (r == 1) ? e1 : e2;
    int base = (r == 0) ? 0 : (r == 1) ? NNEWS : (NNEWS + NUSER);
    rank[idx] = atomicAdd(&cu[base + ei[NE + e]], 1);
}

__global__ __launch_bounds__(256) void scan_part_kernel(const int* __restrict__ cu,
                                                        int* __restrict__ bsum) {
    int i = blockIdx.x * 256 + threadIdx.x;
    int v = (i < NTOT) ? cu[i] : 0;
    #pragma unroll
    for (int o = 1; o < 64; o <<= 1) v += __shfl_xor(v, o);
    __shared__ int ws_[4];
    if ((threadIdx.x & 63) == 0) ws_[threadIdx.x >> 6] = v;
    __syncthreads();
    if (threadIdx.x == 0) bsum[blockIdx.x] = ws_[0] + ws_[1] + ws_[2] + ws_[3];
}

__global__ __launch_bounds__(1024) void scan_top_kernel(const int* __restrict__ bsum,
                                                        int* __restrict__ boff,
                                                        int* __restrict__ jrp) {
    __shared__ int wsum[16];
    int tid = threadIdx.x, lane = tid & 63, w = tid >> 6;
    int v = (tid < NSB) ? bsum[tid] : 0;
    int x = v;
    #pragma unroll
    for (int o = 1; o < 64; o <<= 1) { int y = __shfl_up(x, o); if (lane >= o) x += y; }
    if (lane == 63) wsum[w] = x;
    __syncthreads();
    if (tid < 16) {
        int t = wsum[tid];
        #pragma unroll
        for (int o = 1; o < 16; o <<= 1) { int y = __shfl_up(t, o); if (tid >= o) t += y; }
        wsum[tid] = t;
    }
    __syncthreads();
    int woff = w ? wsum[w - 1] : 0;
    if (tid < NSB) boff[tid] = woff + x - v;
    if (tid == 0) jrp[NTOT] = 3 * NE;
}

__global__ __launch_bounds__(256) void scan_fin_kernel(const int* __restrict__ cu,
                                                       const int* __restrict__ boff,
                                                       int* __restrict__ jrp) {
    __shared__ int wsum[4];
    int tid = threadIdx.x, lane = tid & 63, w = tid >> 6;
    int i = blockIdx.x * 256 + tid;
    int v = (i < NTOT) ? cu[i] : 0;
    int x = v;
    #pragma unroll
    for (int o = 1; o < 64; o <<= 1) { int y = __shfl_up(x, o); if (lane >= o) x += y; }
    if (lane == 63) wsum[w] = x;
    __syncthreads();
    int woff = 0;
    #pragma unroll
    for (int k = 0; k < 4; ++k) if (k < w) woff += wsum[k];
    int excl = boff[blockIdx.x] + woff + x - v;
    if (i < NTOT) jrp[i] = excl;
}

__global__ void fill_kernel(const int* __restrict__ e0, const int* __restrict__ e1,
                            const int* __restrict__ e2, const int* __restrict__ jrp,
                            const int* __restrict__ rank, int* __restrict__ cl) {
    int idx = blockIdx.x * 256 + threadIdx.x;
    if (idx >= 3 * NE) return;
    int r = idx / NE, e = idx - r * NE;
    const int* ei = (r == 0) ? e0 : (r == 1) ? e1 : e2;
    int base = (r == 0) ? 0 : (r == 1) ? NNEWS : (NNEWS + NUSER);
    int dst = ei[NE + e], src = ei[e];
    cl[jrp[base + dst] + rank[idx]] = src;
}

// ---------------- fused projection GEMM (R7) ----------------
// R6 analysis: GEMM bucket ~390us >> 105us byte-floor; pipelining(R1)=0, bytes(R2)<model,
// stores(R6)=+14 -> residual is 22 serialized dispatches (launch+stage ramp+drain, news
// kernels can't fill 256 CUs). Fuse all 5 per-layer projection GEMMs into ONE dispatch via
// a block-range job table. Math/staging/LDS-epilogue identical to v8. T=4 for all jobs
// (TLP now comes from sibling jobs). All job selects are block-uniform.
struct GJob {
    const void* A;            // x input (fp32 l0 / fp16 l1)
    const _Float16* W0;
    const _Float16* W1;       // null if nout2==0
    const float* b0;
    const float* b1;
    _Float16* o0;
    _Float16* o1;
    _Float16* x16;            // non-null: dual-write fp16-converted x (l0 q jobs)
    int ostride, N, blk0, nout2;
};
struct GJobs { GJob j[5]; int njobs; };

template<bool IN_HALF>
__global__ __launch_bounds__(256) void gemm_G(GJobs gj)
{
    __shared__ _Float16 sW[32768];   // 64 KB (both matrices when nout2)
    __shared__ _Float16 sE[8192];    // 16 KB coalescing buffer
    const int tid = threadIdx.x;
    const int lane = tid & 63;
    const int m = lane & 15, quad = lane >> 4, wave = tid >> 6;

    GJob J = gj.j[0];                                  // constant indices only
    if (gj.njobs > 1 && (int)blockIdx.x >= gj.j[1].blk0) J = gj.j[1];
    if (gj.njobs > 2 && (int)blockIdx.x >= gj.j[2].blk0) J = gj.j[2];
    if (gj.njobs > 3 && (int)blockIdx.x >= gj.j[3].blk0) J = gj.j[3];
    if (gj.njobs > 4 && (int)blockIdx.x >= gj.j[4].blk0) J = gj.j[4];

    const int n8 = J.nout2 ? 4096 : 2048;
    for (int i = tid; i < n8; i += 256) {
        const _Float16* src = (i < 2048) ? (J.W0 + (size_t)i * 8)
                                         : (J.W1 + (size_t)(i - 2048) * 8);
        *(f16x8*)(sW + (size_t)i * 8) = *(const f16x8*)src;
    }
    __syncthreads();

    const int tbase = ((int)blockIdx.x - J.blk0) * 4;
    for (int t = 0; t < 4; ++t) {
        const int row0 = (tbase + t) * 64;
        if (row0 >= J.N) break;                        // block-uniform
        const int node  = row0 + wave * 16 + m;
        const int nodec = (node < J.N) ? node : (J.N - 1);

        f16x8 xf[4];
        if constexpr (IN_HALF) {
            const _Float16* A_ = (const _Float16*)J.A + (size_t)nodec * 128 + quad * 8;
            xf[0] = *(const f16x8*)(A_);
            xf[1] = *(const f16x8*)(A_ + 32);
            xf[2] = *(const f16x8*)(A_ + 64);
            xf[3] = *(const f16x8*)(A_ + 96);
        } else {
            const float* A_ = (const float*)J.A + (size_t)nodec * 128 + quad * 8;
            #pragma unroll
            for (int kt = 0; kt < 4; ++kt) {
                f32x4 u = *(const f32x4*)(A_ + kt * 32);
                f32x4 v = *(const f32x4*)(A_ + kt * 32 + 4);
                xf[kt] = (f16x8){(_Float16)u[0], (_Float16)u[1], (_Float16)u[2], (_Float16)u[3],
                                 (_Float16)v[0], (_Float16)v[1], (_Float16)v[2], (_Float16)v[3]};
            }
        }

        if constexpr (!IN_HALF) {                      // fp16 x side-channel (l0 q jobs)
            if (J.x16 && node < J.N) {
                _Float16* xd = J.x16 + (size_t)node * 128 + quad * 8;
                *(f16x8*)(xd)      = xf[0];
                *(f16x8*)(xd + 32) = xf[1];
                *(f16x8*)(xd + 64) = xf[2];
                *(f16x8*)(xd + 96) = xf[3];
            }
        }

        f32x4 acc0[8], acc1[8];
        #pragma unroll
        for (int u = 0; u < 8; ++u) {
            acc0[u] = (f32x4){0.f, 0.f, 0.f, 0.f};
            acc1[u] = (f32x4){0.f, 0.f, 0.f, 0.f};
        }
        #pragma unroll
        for (int kt = 0; kt < 4; ++kt) {
            #pragma unroll
            for (int ct = 0; ct < 8; ++ct) {
                f16x8 wf0 = *(const f16x8*)(sW + ((kt * 8 + ct) * 64 + lane) * 8);
                acc0[ct] = __builtin_amdgcn_mfma_f32_16x16x32_f16(wf0, xf[kt], acc0[ct], 0, 0, 0);
            }
        }
        if (J.nout2) {
            #pragma unroll
            for (int kt = 0; kt < 4; ++kt) {
                #pragma unroll
                for (int ct = 0; ct < 8; ++ct) {
                    f16x8 wf1 = *(const f16x8*)(sW + 16384 + ((kt * 8 + ct) * 64 + lane) * 8);
                    acc1[ct] = __builtin_amdgcn_mfma_f32_16x16x32_f16(wf1, xf[kt], acc1[ct], 0, 0, 0);
                }
            }
        }

        const int r16 = wave * 16 + m;
        const int swz = (r16 & 7) << 4;
        {   // matrix 0: LDS transpose -> coalesced f16x8 stores
            f16x4 h[8];
            #pragma unroll
            for (int ct = 0; ct < 8; ++ct) {
                int c = ct * 16 + quad * 4;
                f32x4 r = acc0[ct] + *(const f32x4*)(J.b0 + c);
                h[ct] = (f16x4){(_Float16)r[0], (_Float16)r[1], (_Float16)r[2], (_Float16)r[3]};
            }
            __syncthreads();
            #pragma unroll
            for (int ct = 0; ct < 8; ++ct)
                *(f16x4*)((char*)sE + r16 * 256 + ((ct * 32 + quad * 8) ^ swz)) = h[ct];
            __syncthreads();
            #pragma unroll
            for (int jj = 0; jj < 4; ++jj) {
                int c = jj * 256 + tid;
                int n16 = c >> 4, w = c & 15;
                f16x8 v = *(const f16x8*)((const char*)sE + n16 * 256 + ((w * 16) ^ ((n16 & 7) << 4)));
                int gnode = row0 + n16;
                if (gnode < J.N)
                    *(f16x8*)(J.o0 + (size_t)gnode * J.ostride + w * 8) = v;
            }
        }
        if (J.nout2) {   // matrix 1 (reuses sE; barriers uniform within block)
            f16x4 h[8];
            #pragma unroll
            for (int ct = 0; ct < 8; ++ct) {
                int c = ct * 16 + quad * 4;
                f32x4 r = acc1[ct] + *(const f32x4*)(J.b1 + c);
                h[ct] = (f16x4){(_Float16)r[0], (_Float16)r[1], (_Float16)r[2], (_Float16)r[3]};
            }
            __syncthreads();
            #pragma unroll
            for (int ct = 0; ct < 8; ++ct)
                *(f16x4*)((char*)sE + r16 * 256 + ((ct * 32 + quad * 8) ^ swz)) = h[ct];
            __syncthreads();
            #pragma unroll
            for (int jj = 0; jj < 4; ++jj) {
                int c = jj * 256 + tid;
                int n16 = c >> 4, w = c & 15;
                f16x8 v = *(const f16x8*)((const char*)sE + n16 * 256 + ((w * 16) ^ ((n16 & 7) << 4)));
                int gnode = row0 + n16;
                if (gnode < J.N)
                    *(f16x8*)(J.o1 + (size_t)gnode * J.ostride + w * 8) = v;
            }
        }
    }
}

// ---------------- fused output-transform GEMM (epilogue) ----------------
struct EJob {
    const _Float16* A;        // agg (gelu'd)
    const _Float16* W0;
    const float* b0;
    void* o0;                 // fp16 (l0, in-place x16) or fp32 (l1, d_out)
    const _Float16* Xold;     // fp16 residual
    const float* skipv;
    int N, blk0;
};
struct EJobs { EJob j[2]; };

template<bool OUT32>
__global__ __launch_bounds__(256) void epi_E(EJobs ej)
{
    __shared__ _Float16 sW[16384];                    // 32 KB
    __shared__ _Float16 sE[OUT32 ? 64 : 8192];        // 16 KB when fp16 out
    const int tid = threadIdx.x;
    const int lane = tid & 63;
    const int m = lane & 15, quad = lane >> 4, wave = tid >> 6;

    EJob J = ej.j[0];
    if ((int)blockIdx.x >= ej.j[1].blk0) J = ej.j[1];

    for (int i = tid; i < 2048; i += 256)
        *(f16x8*)(sW + (size_t)i * 8) = *(const f16x8*)(J.W0 + (size_t)i * 8);
    __syncthreads();

    float sv = J.skipv[0];
    float aS = 1.0f / (1.0f + expf(-sv));
    float bSk = 1.0f - aS;

    const int tbase = ((int)blockIdx.x - J.blk0) * 2;   // T=2
    for (int t = 0; t < 2; ++t) {
        const int row0 = (tbase + t) * 64;
        if (row0 >= J.N) break;
        const int node  = row0 + wave * 16 + m;
        const int nodec = (node < J.N) ? node : (J.N - 1);

        // residual (fp16), loaded early so it completes under the MFMAs
        f16x4 xh[8];
        {
            const _Float16* Xo = J.Xold + (size_t)nodec * 128 + quad * 4;
            #pragma unroll
            for (int ct = 0; ct < 8; ++ct) xh[ct] = *(const f16x4*)(Xo + ct * 16);
        }

        f16x8 xf[4];
        {
            const _Float16* A_ = J.A + (size_t)nodec * 128 + quad * 8;
            xf[0] = *(const f16x8*)(A_);
            xf[1] = *(const f16x8*)(A_ + 32);
            xf[2] = *(const f16x8*)(A_ + 64);
            xf[3] = *(const f16x8*)(A_ + 96);
        }

        f32x4 acc0[8];
        #pragma unroll
        for (int u = 0; u < 8; ++u) acc0[u] = (f32x4){0.f, 0.f, 0.f, 0.f};
        #pragma unroll
        for (int kt = 0; kt < 4; ++kt) {
            #pragma unroll
            for (int ct = 0; ct < 8; ++ct) {
                f16x8 wf0 = *(const f16x8*)(sW + ((kt * 8 + ct) * 64 + lane) * 8);
                acc0[ct] = __builtin_amdgcn_mfma_f32_16x16x32_f16(wf0, xf[kt], acc0[ct], 0, 0, 0);
            }
        }

        if constexpr (OUT32) {
            if (node < J.N) {
                #pragma unroll
                for (int ct = 0; ct < 8; ++ct) {
                    int c = ct * 16 + quad * 4;
                    f32x4 r = acc0[ct] + *(const f32x4*)(J.b0 + c);
                    #pragma unroll
                    for (int jj = 0; jj < 4; ++jj)
                        r[jj] = fmaxf(aS * r[jj] + bSk * (float)xh[ct][jj], 0.f);
                    *(f32x4*)((float*)J.o0 + (size_t)node * 128 + c) = r;
                }
            }
        } else {
            const int r16 = wave * 16 + m;
            const int swz = (r16 & 7) << 4;
            f16x4 h[8];
            #pragma unroll
            for (int ct = 0; ct < 8; ++ct) {
                int c = ct * 16 + quad * 4;
                f32x4 r = acc0[ct] + *(const f32x4*)(J.b0 + c);
                #pragma unroll
                for (int jj = 0; jj < 4; ++jj)
                    r[jj] = fmaxf(aS * r[jj] + bSk * (float)xh[ct][jj], 0.f);
                h[ct] = (f16x4){(_Float16)r[0], (_Float16)r[1], (_Float16)r[2], (_Float16)r[3]};
            }
            __syncthreads();
            #pragma unroll
            for (int ct = 0; ct < 8; ++ct)
                *(f16x4*)((char*)sE + r16 * 256 + ((ct * 32 + quad * 8) ^ swz)) = h[ct];
            __syncthreads();
            #pragma unroll
            for (int jj = 0; jj < 4; ++jj) {
                int c = jj * 256 + tid;
                int n16 = c >> 4, w = c & 15;
                f16x8 v = *(const f16x8*)((const char*)sE + n16 * 256 + ((w * 16) ^ ((n16 & 7) << 4)));
                int gnode = row0 + n16;
                if (gnode < J.N)
                    *(f16x8*)((_Float16*)J.o0 + (size_t)gnode * 128 + w * 8) = v;
            }
        }
    }
}

// ---------------- attention: fused news+user dispatch (inner loop = v5, untouched) --------
// v5 core: 36 VGPR, 2-chain, 4 nodes/wave. R4(v6)/R5(v7) proved widening/merging regresses
// (VALU-issue + occupancy). Fusion here is purely at the BLOCK level: first nbn blocks do
// news (1 relation), rest do user (2 relations) -> the news tail fills with user work.
__device__ __forceinline__ void attn_core(
    const _Float16* q, const _Float16* kv1, const int* rp1,
    const _Float16* kv2, const int* rp2, const int* cl,
    _Float16* agg, int d, int two, int sub)
{
    f16x8 qh = *(const f16x8*)(q + (size_t)d * 128 + sub * 8);
    float acc[8] = {0.f, 0.f, 0.f, 0.f, 0.f, 0.f, 0.f, 0.f};

    for (int rel = 0; rel < 1 + two; ++rel) {
        const _Float16* kv = rel ? kv2 : kv1;
        const int* rp = rel ? rp2 : rp1;
        int e0 = rp[d], e1 = rp[d + 1];
        float den = 0.f;
        float s[8] = {0.f, 0.f, 0.f, 0.f, 0.f, 0.f, 0.f, 0.f};
        int e = e0;
        for (; e + 1 < e1; e += 2) {
            int s0 = cl[e], s1 = cl[e + 1];
            const _Float16* r0 = kv + (size_t)s0 * 256;
            const _Float16* r1 = kv + (size_t)s1 * 256;
            f16x8 k0 = *(const f16x8*)(r0 + sub * 8);
            f16x8 v0 = *(const f16x8*)(r0 + 128 + sub * 8);
            f16x8 k1 = *(const f16x8*)(r1 + sub * 8);
            f16x8 v1 = *(const f16x8*)(r1 + 128 + sub * 8);
            float p0 = 0.f, p1 = 0.f;
#if __has_builtin(__builtin_amdgcn_fdot2)
            const f16x2* qp = (const f16x2*)&qh;
            const f16x2* a0 = (const f16x2*)&k0;
            const f16x2* a1 = (const f16x2*)&k1;
            #pragma unroll
            for (int j = 0; j < 4; ++j) {
                p0 = __builtin_amdgcn_fdot2(a0[j], qp[j], p0, false);
                p1 = __builtin_amdgcn_fdot2(a1[j], qp[j], p1, false);
            }
#else
            #pragma unroll
            for (int j = 0; j < 8; ++j) {
                p0 += (float)k0[j] * (float)qh[j];
                p1 += (float)k1[j] * (float)qh[j];
            }
#endif
            p0 += __shfl_xor(p0, 1); p1 += __shfl_xor(p1, 1);
            p0 += __shfl_xor(p0, 2); p1 += __shfl_xor(p1, 2);
            float w0 = exp2f(p0), w1 = exp2f(p1);
            den += w0 + w1;
            #pragma unroll
            for (int j = 0; j < 8; ++j) s[j] += w0 * (float)v0[j] + w1 * (float)v1[j];
        }
        if (e < e1) {
            int s0 = cl[e];
            const _Float16* r0 = kv + (size_t)s0 * 256;
            f16x8 k0 = *(const f16x8*)(r0 + sub * 8);
            f16x8 v0 = *(const f16x8*)(r0 + 128 + sub * 8);
            float p0 = 0.f;
#if __has_builtin(__builtin_amdgcn_fdot2)
            const f16x2* qp = (const f16x2*)&qh;
            const f16x2* a0 = (const f16x2*)&k0;
            #pragma unroll
            for (int j = 0; j < 4; ++j) p0 = __builtin_amdgcn_fdot2(a0[j], qp[j], p0, false);
#else
            #pragma unroll
            for (int j = 0; j < 8; ++j) p0 += (float)k0[j] * (float)qh[j];
#endif
            p0 += __shfl_xor(p0, 1);
            p0 += __shfl_xor(p0, 2);
            float w0 = exp2f(p0);
            den += w0;
            #pragma unroll
            for (int j = 0; j < 8; ++j) s[j] += w0 * (float)v0[j];
        }
        if (den > 0.f) {
            float inv = 1.f / den;
            #pragma unroll
            for (int j = 0; j < 8; ++j) acc[j] += s[j] * inv;
        }
    }

    f16x8 o;
    #pragma unroll
    for (int j = 0; j < 8; ++j) o[j] = (_Float16)gelu_f(acc[j]);
    *(f16x8*)(agg + (size_t)d * 128 + sub * 8) = o;
}

__global__ __launch_bounds__(256) void attn_v5(
    const _Float16* __restrict__ q,
    const _Float16* __restrict__ kv1, const int* __restrict__ rp1,
    const _Float16* __restrict__ kv2, const int* __restrict__ rp2,
    const int* __restrict__ cl,
    _Float16* __restrict__ agg, int Ndst, int two)
{
    int d = blockIdx.x * 16 + (threadIdx.x >> 4);
    if (d >= Ndst) return;
    attn_core(q, kv1, rp1, kv2, rp2, cl, agg, d, two, threadIdx.x & 15);
}

__global__ __launch_bounds__(256) void attn_A(
    const _Float16* __restrict__ qn, const _Float16* __restrict__ kvn,
    const int* __restrict__ rpn, _Float16* __restrict__ aggn, int Nn,
    const _Float16* __restrict__ qu, const _Float16* __restrict__ kvu1,
    const int* __restrict__ rpu1, const _Float16* __restrict__ kvu2,
    const int* __restrict__ rpu2, _Float16* __restrict__ aggu, int Nu,
    const int* __restrict__ cl, int nbn)
{
    bool news = (int)blockIdx.x < nbn;
    int brel = news ? blockIdx.x : blockIdx.x - nbn;
    int d = brel * 16 + (threadIdx.x >> 4);
    int N = news ? Nn : Nu;
    if (d >= N) return;
    attn_core(news ? qn : qu,
              news ? kvn : kvu1, news ? rpn : rpu1,
              kvu2, rpu2, cl,
              news ? aggn : aggu, d, news ? 0 : 1, threadIdx.x & 15);
}

// ---------------- orchestration ----------------
extern "C" void kernel_launch(void* const* d_in, const int* in_sizes, int n_in,
                              void* d_out, int out_size, void* d_ws, size_t ws_size,
                              hipStream_t stream)
{
    const float* x_user = (const float*)d_in[0];
    const float* x_news = (const float*)d_in[1];
    const int* ei0 = (const int*)d_in[2];
    const int* ei1 = (const int*)d_in[3];
    const int* ei2 = (const int*)d_in[4];
    const float* Wk = (const float*)d_in[5];
    const float* bk = (const float*)d_in[6];
    const float* Wq = (const float*)d_in[7];
    const float* bq = (const float*)d_in[8];
    const float* Wv = (const float*)d_in[9];
    const float* bv = (const float*)d_in[10];
    const float* Wa = (const float*)d_in[11];
    const float* ba = (const float*)d_in[12];
    const float* skip = (const float*)d_in[13];
    const float* a_rel = (const float*)d_in[14];
    const float* m_rel = (const float*)d_in[15];
    const float* p_rel = (const float*)d_in[16];

    float* ws = (float*)d_ws;
    _Float16* q_user  = (_Float16*)(ws + OFF_QU);
    _Float16* q_news  = (_Float16*)(ws + OFF_QN);
    _Float16* agg_u   = (_Float16*)(ws + OFF_AGU);
    _Float16* agg_n   = (_Float16*)(ws + OFF_AGN);
    _Float16* kv_big  = (_Float16*)(ws + OFF_KVB);
    _Float16* kv_sm   = (_Float16*)(ws + OFF_KVS);
    _Float16* wkf = (_Float16*)(ws + OFF_WF);
    _Float16* wvf = wkf + 6 * 16384;
    _Float16* wqf = wvf + 6 * 16384;
    _Float16* waf = wqf + 4 * 16384;
    float* bke = ws + OFF_BE;
    float* bve = bke + 768;
    int* ib   = (int*)(ws + OFF_INT);
    int* cu   = ib + IO_CU;
    int* jrp  = ib + IO_JRP;
    int* bsum = ib + IO_BSUM;
    int* boff = ib + IO_BOFF;
    int* cl   = ib + IO_CL;
    int* rank = ib + IO_RANK;
    _Float16* x16u = (_Float16*)(ws + OFF_X16U);
    _Float16* x16n = (_Float16*)(ws + OFF_X16N);
    _Float16* kv_big2 = (_Float16*)(ws + OFF_KVB2);
    const int* rp0 = jrp;
    const int* rp1 = jrp + NNEWS;
    const int* rp2 = jrp + NNEWS + NUSER;

    const bool roomy = ws_size >= WS_NEED_ROOMY;    // kv_big2 fits -> full fusion path

    // ---- weight prep + counter zero ----
    prep_weights_kernel<<<(NPREP + NTOT + 255) / 256, 256, 0, stream>>>(
        Wk, bk, Wv, bv, Wq, Wa, a_rel, m_rel, p_rel,
        wkf, bke, wvf, bve, wqf, waf, cu);

    // ---- CSR build ----
    int g3e = (3 * NE + 255) / 256;
    histrank_kernel<<<g3e, 256, 0, stream>>>(ei0, ei1, ei2, cu, rank);
    scan_part_kernel<<<NSB, 256, 0, stream>>>(cu, bsum);
    scan_top_kernel<<<1, 1024, 0, stream>>>(bsum, boff, jrp);
    scan_fin_kernel<<<NSB, 256, 0, stream>>>(cu, boff, jrp);
    fill_kernel<<<g3e, 256, 0, stream>>>(ei0, ei1, ei2, jrp, rank, cl);

    float* out_user = (float*)d_out;
    float* out_news = (float*)d_out + (size_t)NUSER * CH;

    const int GBU = ((NUSER + 63) / 64 + 3) / 4;    // 391 blocks per user GEMM job (T=4)
    const int GBN = ((NNEWS + 63) / 64 + 3) / 4;    // 79 per news job
    const int EBU = ((NUSER + 63) / 64 + 1) / 2;    // 782 (T=2)
    const int EBN = ((NNEWS + 63) / 64 + 1) / 2;    // 157
    const int ABN = (NNEWS + 15) / 16;              // 1250
    const int ABU = (NUSER + 15) / 16;              // 6250

    for (int l = 0; l < 2; ++l) {
        _Float16* wkf_l = wkf + (size_t)l * 3 * 16384;
        _Float16* wvf_l = wvf + (size_t)l * 3 * 16384;
        _Float16* wqf_l = wqf + (size_t)l * 2 * 16384;
        _Float16* waf_l = waf + (size_t)l * 2 * 16384;
        float* bke_l = bke + (size_t)l * 384;
        float* bve_l = bve + (size_t)l * 384;
        const void* xu_in = l ? (const void*)x16u : (const void*)x_user;
        const void* xn_in = l ? (const void*)x16n : (const void*)x_news;

        // ---- G: fused projection GEMMs ----
        GJobs gj{};
        int nb = 0;
        // q_user
        gj.j[0] = {xu_in, wqf_l, nullptr, bq + (size_t)(l * 2 + 0) * 128, nullptr,
                   q_user, nullptr, l ? nullptr : x16u, 128, NUSER, nb, 0};
        nb += GBU;
        // q_news
        gj.j[1] = {xn_in, wqf_l + 16384, nullptr, bq + (size_t)(l * 2 + 1) * 128, nullptr,
                   q_news, nullptr, l ? nullptr : x16n, 128, NNEWS, nb, 0};
        nb += GBN;
        // kv0 (user src -> kv_big)
        gj.j[2] = {xu_in, wkf_l, wvf_l, bke_l, bve_l,
                   kv_big, kv_big + 128, nullptr, 256, NUSER, nb, 1};
        nb += GBU;
        // kv1 (news src -> kv_sm)
        gj.j[3] = {xn_in, wkf_l + 16384, wvf_l + 16384, bke_l + 128, bve_l + 128,
                   kv_sm, kv_sm + 128, nullptr, 256, NNEWS, nb, 1};
        nb += GBN;
        gj.njobs = 4;
        if (roomy) {   // kv2 (user src -> kv_big2) fused in
            gj.j[4] = {xu_in, wkf_l + 32768, wvf_l + 32768, bke_l + 256, bve_l + 256,
                       kv_big2, kv_big2 + 128, nullptr, 256, NUSER, nb, 1};
            nb += GBU;
            gj.njobs = 5;
        }
        if (l == 0) gemm_G<false><<<nb, 256, 0, stream>>>(gj);
        else        gemm_G<true ><<<nb, 256, 0, stream>>>(gj);

        // ---- attention ----
        if (roomy) {
            attn_A<<<ABN + ABU, 256, 0, stream>>>(
                q_news, kv_big, rp0, agg_n, NNEWS,
                q_user, kv_sm, rp1, kv_big2, rp2, agg_u, NUSER, cl, ABN);
        } else {
            attn_v5<<<ABN, 256, 0, stream>>>(
                q_news, kv_big, rp0, nullptr, nullptr, cl, agg_n, NNEWS, 0);
            GJobs g2{};
            g2.j[0] = {xu_in, wkf_l + 32768, wvf_l + 32768, bke_l + 256, bve_l + 256,
                       kv_big, kv_big + 128, nullptr, 256, NUSER, 0, 1};
            g2.njobs = 1;
            if (l == 0) gemm_G<false><<<GBU, 256, 0, stream>>>(g2);
            else        gemm_G<true ><<<GBU, 256, 0, stream>>>(g2);
            attn_v5<<<ABU, 256, 0, stream>>>(
                q_user, kv_sm, rp1, kv_big, rp2, cl, agg_u, NUSER, 1);
        }

        // ---- E: fused output transforms ----
        // l0: fp16 in-place into x16 (becomes layer-1 activation). l1: fp32 d_out.
        EJobs ej{};
        ej.j[0] = {agg_u, waf_l, ba + (size_t)(l * 2 + 0) * 128,
                   l ? (void*)out_user : (void*)x16u, x16u, skip + l * 2 + 0, NUSER, 0};
        ej.j[1] = {agg_n, waf_l + 16384, ba + (size_t)(l * 2 + 1) * 128,
                   l ? (void*)out_news : (void*)x16n, x16n, skip + l * 2 + 1, NNEWS, EBU};
        if (l == 0) epi_E<false><<<EBU + EBN, 256, 0, stream>>>(ej);
        else        epi_E<true ><<<EBU + EBN, 256, 0, stream>>>(ej);
    }
    (void)in_sizes; (void)n_in; (void)out_size;
}